// Round 1
// baseline (1233.722 us; speedup 1.0000x reference)
//
#include <hip/hip_runtime.h>
#include <math.h>

#define NPROT 50000
#define NCLS  5000
#define DIMP  1280
#define DIMC  256
#define HIDD  128

typedef float4 f4;

// ---------- helpers ----------
__device__ __forceinline__ unsigned encf(float x){
    unsigned u = __float_as_uint(x);
    return (u & 0x80000000u) ? ~u : (u | 0x80000000u);
}
__device__ __forceinline__ float decf(unsigned u){
    return __uint_as_float((u & 0x80000000u) ? (u & 0x7FFFFFFFu) : ~u);
}
__device__ __forceinline__ void atomAddF(float* p, float v){
    unsafeAtomicAdd(p, v);   // native global_atomic_add_f32 on gfx950
}

// ---------- generic tiled f32 GEMM: C[M,N] = A[M,K] @ B[K,N], row-major ----------
// requires N % 64 == 0, K % 16 == 0; M guarded.
__global__ __launch_bounds__(256) void gemm64(const float* __restrict__ A,
                                              const float* __restrict__ B,
                                              float* __restrict__ C,
                                              int M, int N, int K){
    __shared__ __align__(16) float As[16][68];   // [kk][m], padded
    __shared__ __align__(16) float Bs[16][64];   // [kk][n]
    const int tid = threadIdx.x;
    const int row0 = blockIdx.y * 64;
    const int col0 = blockIdx.x * 64;
    const int ty = tid >> 4;      // 0..15
    const int tx = tid & 15;      // 0..15

    const int m  = tid >> 2;            // 0..63  (A-load row)
    const int kq = (tid & 3) << 2;      // 0,4,8,12
    const int kb = tid >> 4;            // 0..15  (B-load k)
    const int c4 = (tid & 15) << 2;     // 0..60

    float acc[4][4];
#pragma unroll
    for(int i=0;i<4;i++)
#pragma unroll
        for(int j=0;j<4;j++) acc[i][j]=0.f;

    const bool arow_ok = (row0 + m) < M;
    const float* Abase = A + (size_t)(row0 + m) * K + kq;
    const float* Bbase = B + col0 + c4 + (size_t)kb * N;

    for(int k0 = 0; k0 < K; k0 += 16){
        f4 av;
        if(arow_ok) av = *(const f4*)(Abase + k0);
        else        av = make_float4(0.f,0.f,0.f,0.f);
        As[kq+0][m]=av.x; As[kq+1][m]=av.y; As[kq+2][m]=av.z; As[kq+3][m]=av.w;
        *(f4*)&Bs[kb][c4] = *(const f4*)(Bbase + (size_t)k0 * N);
        __syncthreads();
#pragma unroll
        for(int kk=0;kk<16;kk++){
            f4 a = *(const f4*)&As[kk][ty<<2];
            f4 b = *(const f4*)&Bs[kk][tx<<2];
            float ar[4]={a.x,a.y,a.z,a.w};
            float br[4]={b.x,b.y,b.z,b.w};
#pragma unroll
            for(int i=0;i<4;i++)
#pragma unroll
                for(int j=0;j<4;j++) acc[i][j] += ar[i]*br[j];
        }
        __syncthreads();
    }
#pragma unroll
    for(int i=0;i<4;i++){
        int r = row0 + (ty<<2) + i;
        if(r < M){
            f4 v = make_float4(acc[i][0],acc[i][1],acc[i][2],acc[i][3]);
            *(f4*)&C[(size_t)r*N + col0 + (tx<<2)] = v;
        }
    }
}

// ---------- narrow GEMM: C[M,8] = A[M,128] @ B[128,8] ----------
__global__ __launch_bounds__(256) void gemm_n8(const float* __restrict__ A,
                                               const float* __restrict__ B8,
                                               float* __restrict__ C, int M){
    __shared__ float Bs[128*8];
    const int tid = threadIdx.x;
    for(int i=tid;i<1024;i+=256) Bs[i]=B8[i];
    __syncthreads();
    const int row = blockIdx.x*32 + (tid>>3);
    const int j = tid & 7;
    if(row >= M) return;
    const float* a = A + (size_t)row*128;
    float s=0.f;
#pragma unroll
    for(int k=0;k<128;k++) s += a[k]*Bs[k*8+j];
    C[(size_t)row*8+j]=s;
}

// ---------- weight prep ----------
// out [K,256]: cols 0..127 <- Wa[K,128], cols 128..255 <- Wb[K,128]
__global__ void build_cat(const float* __restrict__ Wa, const float* __restrict__ Wb,
                          float* __restrict__ out, int K){
    int t = blockIdx.x*256 + threadIdx.x;
    if(t >= K*256) return;
    int k = t >> 8, j = t & 255;
    out[t] = (j<128) ? Wa[k*128+j] : Wb[k*128 + (j-128)];
}

// proj[k][colbase+h] = sum_c W[k, h*128+c] * a[h,c]   (W: [128,512], a: [4,128])
__global__ void fold_att(const float* __restrict__ W, const float* __restrict__ a,
                         float* __restrict__ proj, int colbase){
    int t = blockIdx.x*256 + threadIdx.x;
    if(t >= 512) return;
    int k = t >> 2, h = t & 3;
    const float* w = W + (size_t)k*512 + h*128;
    const float* av = a + h*128;
    float s=0.f;
    for(int c=0;c<128;c++) s += w[c]*av[c];
    proj[k*8 + colbase + h] = s;
}

__global__ void fold_link(const float* __restrict__ lpW, const float* __restrict__ lpb,
                          const float* __restrict__ lcW, const float* __restrict__ lcb,
                          const float* __restrict__ linkW,
                          float* __restrict__ w_p, float* __restrict__ w_c,
                          float* __restrict__ cpc){
    int t = threadIdx.x;
    if(t < 128){
        float s=0.f;
        for(int o=0;o<128;o++) s += lpW[t*128+o]*linkW[o];
        w_p[t]=s;
    } else {
        int j=t-128;
        float s=0.f;
        for(int o=0;o<128;o++) s += lcW[j*128+o]*linkW[128+o];
        w_c[j]=s;
    }
    if(t==0){ float s=0.f; for(int o=0;o<128;o++) s+=lpb[o]*linkW[o];      cpc[0]=s; }
    if(t==1){ float s=0.f; for(int o=0;o<128;o++) s+=lcb[o]*linkW[128+o];  cpc[1]=s; }
}

// ---------- edge kernels ----------
__global__ void deg_kernel(const int* __restrict__ src, const int* __restrict__ dst,
                           int* __restrict__ deg_p, int* __restrict__ deg_c, int E){
    int e = blockIdx.x*256 + threadIdx.x;
    if(e>=E) return;
    atomicAdd(&deg_p[src[e]],1);
    atomicAdd(&deg_c[dst[e]],1);
}

// SAGE aggregation: acc_c[d] += P1row(s)[0:128];  acc_p[s] += C1row(d)[0:128]
__global__ __launch_bounds__(256) void sage_agg(const int* __restrict__ src, const int* __restrict__ dst,
                                                const float* __restrict__ P1, const float* __restrict__ C1,
                                                float* __restrict__ acc_c, float* __restrict__ acc_p){
    int e = blockIdx.x;
    int s = src[e], d = dst[e];
    int j = threadIdx.x;
    if(j < 128){
        atomAddF(&acc_c[(size_t)d*128+j], P1[(size_t)s*256+j]);
    } else {
        int j2 = j-128;
        atomAddF(&acc_p[(size_t)s*128+j2], C1[(size_t)d*256+j2]);
    }
}

// h = relu(acc/max(deg,1) + bl + self[:,128:256])
__global__ void build_h(const float* __restrict__ acc, const int* __restrict__ deg,
                        const float* __restrict__ self, const float* __restrict__ bl,
                        float* __restrict__ h, int Nnode){
    int t = blockIdx.x*256 + threadIdx.x;
    if(t >= Nnode*128) return;
    int n = t >> 7, j = t & 127;
    float cnt = (float)max(deg[n],1);
    float v = acc[t]/cnt + bl[j] + self[(size_t)n*256 + 128 + j];
    h[t] = fmaxf(v, 0.f);
}

// pass 1: leaky-relu logits + segment max (monotone-uint atomicMax)
__global__ void att_max(const int* __restrict__ src, const int* __restrict__ dst,
                        const float* __restrict__ attP, const float* __restrict__ attC,
                        float* __restrict__ att1, float* __restrict__ att2,
                        unsigned* __restrict__ emax_c, unsigned* __restrict__ emax_p, int E){
    int t = blockIdx.x*256 + threadIdx.x;
    if(t >= E*4) return;
    int e = t >> 2, h = t & 3;
    int s = src[e], d = dst[e];
    float e1 = attP[s*8+h]   + attC[d*8+h];        // p->c : als_p + ald_c
    e1 = e1 > 0.f ? e1 : 0.2f*e1;
    float e2 = attC[d*8+4+h] + attP[s*8+4+h];      // c->p : als_c + ald_p
    e2 = e2 > 0.f ? e2 : 0.2f*e2;
    att1[t] = e1;  att2[t] = e2;
    atomicMax(&emax_c[d*4+h], encf(e1));
    atomicMax(&emax_p[s*4+h], encf(e2));
}

// pass 2: exp(e - max) and denominators
__global__ void att_exp(const int* __restrict__ src, const int* __restrict__ dst,
                        float* __restrict__ att1, float* __restrict__ att2,
                        const unsigned* __restrict__ emax_c, const unsigned* __restrict__ emax_p,
                        float* __restrict__ den_c, float* __restrict__ den_p, int E){
    int t = blockIdx.x*256 + threadIdx.x;
    if(t >= E*4) return;
    int e = t >> 2, h = t & 3;
    int s = src[e], d = dst[e];
    float ee1 = expf(att1[t] - decf(emax_c[d*4+h]));
    float ee2 = expf(att2[t] - decf(emax_p[s*4+h]));
    att1[t]=ee1; att2[t]=ee2;
    atomAddF(&den_c[d*4+h], ee1);
    atomAddF(&den_p[s*4+h], ee2);
}

// pass 3: weighted aggregation with head-mean folded in (x0.25)
__global__ __launch_bounds__(256) void gat_agg(const int* __restrict__ src, const int* __restrict__ dst,
                                               const float* __restrict__ att1, const float* __restrict__ att2,
                                               const float* __restrict__ den_c, const float* __restrict__ den_p,
                                               const float* __restrict__ hs_p, const float* __restrict__ hs_c,
                                               float* __restrict__ acc_gc, float* __restrict__ acc_gp){
    __shared__ float al[8];
    int e = blockIdx.x;
    int s = src[e], d = dst[e];
    int tid = threadIdx.x;
    if(tid < 4)      al[tid]   = att1[e*4+tid]   / den_c[d*4+tid];
    else if(tid < 8) al[tid]   = att2[e*4+tid-4] / den_p[s*4+tid-4];
    __syncthreads();
    if(tid < 128){
        float sum = 0.f;
#pragma unroll
        for(int h=0;h<4;h++) sum += al[h]*hs_p[(size_t)s*512 + h*128 + tid];
        atomAddF(&acc_gc[(size_t)d*128 + tid], 0.25f*sum);
    } else {
        int j = tid - 128;
        float sum = 0.f;
#pragma unroll
        for(int h=0;h<4;h++) sum += al[4+h]*hs_c[(size_t)d*512 + h*128 + j];
        atomAddF(&acc_gp[(size_t)s*128 + j], 0.25f*sum);
    }
}

// u[n] = sum_j relu(acc[n,j]+b[j]) * w[j] + cpc[cidx]   (one wave per node)
__global__ __launch_bounds__(256) void node_u(const float* __restrict__ acc, const float* __restrict__ b,
                                              const float* __restrict__ w, const float* __restrict__ cpc, int cidx,
                                              float* __restrict__ u, int Nnode){
    int tid = threadIdx.x;
    int node = blockIdx.x*4 + (tid>>6);
    int lane = tid & 63;
    if(node >= Nnode) return;
    int j = lane*2;
    float2 v = *(const float2*)&acc[(size_t)node*128 + j];
    float p = fmaxf(v.x + b[j],   0.f)*w[j]
            + fmaxf(v.y + b[j+1], 0.f)*w[j+1];
#pragma unroll
    for(int off=32; off; off>>=1) p += __shfl_down(p, off);
    if(lane==0) u[node] = p + cpc[cidx];
}

__global__ void link_out(const int* __restrict__ els, const int* __restrict__ eld,
                         const float* __restrict__ u_p, const float* __restrict__ u_c,
                         const float* __restrict__ linkb, float* __restrict__ out, int EL){
    int i = blockIdx.x*256 + threadIdx.x;
    if(i >= EL) return;
    float x = u_p[els[i]] + u_c[eld[i]] + linkb[0];
    out[i] = 1.f/(1.f + expf(-x));
}

// ---------- host ----------
extern "C" void kernel_launch(void* const* d_in, const int* in_sizes, int n_in,
                              void* d_out, int out_size, void* d_ws, size_t ws_size,
                              hipStream_t stream){
    const float* x_p  = (const float*)d_in[0];
    const float* x_c  = (const float*)d_in[1];
    const int*   src  = (const int*)d_in[2];
    const int*   dst  = (const int*)d_in[3];
    const int*   els  = (const int*)d_in[4];
    const int*   eld  = (const int*)d_in[5];
    const float* sage_pc_Wl = (const float*)d_in[6];
    const float* sage_pc_bl = (const float*)d_in[7];
    const float* sage_pc_Wr = (const float*)d_in[8];
    const float* sage_cp_Wl = (const float*)d_in[9];
    const float* sage_cp_bl = (const float*)d_in[10];
    const float* sage_cp_Wr = (const float*)d_in[11];
    const float* gat_pc_Wsrc = (const float*)d_in[12];
    const float* gat_pc_Wdst = (const float*)d_in[13];
    const float* gat_pc_asrc = (const float*)d_in[14];
    const float* gat_pc_adst = (const float*)d_in[15];
    const float* gat_pc_b    = (const float*)d_in[16];
    const float* gat_cp_Wsrc = (const float*)d_in[17];
    const float* gat_cp_Wdst = (const float*)d_in[18];
    const float* gat_cp_asrc = (const float*)d_in[19];
    const float* gat_cp_adst = (const float*)d_in[20];
    const float* gat_cp_b    = (const float*)d_in[21];
    const float* lin_p_W = (const float*)d_in[22];
    const float* lin_p_b = (const float*)d_in[23];
    const float* lin_c_W = (const float*)d_in[24];
    const float* lin_c_b = (const float*)d_in[25];
    const float* link_W  = (const float*)d_in[26];
    const float* link_b  = (const float*)d_in[27];

    const int E  = in_sizes[2];
    const int EL = in_sizes[4];

    float* ws = (float*)d_ws;
    size_t off = 0;
    auto alloc = [&](size_t n)->float*{ float* p = ws + off; off += (n + 3) & ~(size_t)3; return p; };

    float* Wcat1 = alloc((size_t)DIMP*256);        // [1280,256]: [Wl_pc | Wr_cp]
    float* WcatC = alloc((size_t)DIMC*256);        // [256,256] : [Wl_cp | Wr_pc]
    float* P1    = alloc((size_t)NPROT*256);       // x_p @ Wcat1
    float* C1    = alloc((size_t)NCLS*256);        // x_c @ WcatC
    float* h_p   = alloc((size_t)NPROT*128);
    float* h_c   = alloc((size_t)NCLS*128);
    float* hs_p  = alloc((size_t)NPROT*512);       // h_p @ gat_pc_Wsrc
    float* hs_c  = alloc((size_t)NCLS*512);        // h_c @ gat_cp_Wsrc
    float* attP  = alloc((size_t)NPROT*8);         // [als_pc | ald_cp]
    float* attC  = alloc((size_t)NCLS*8);          // [ald_pc | als_cp]
    float* projP = alloc(128*8);
    float* projC = alloc(128*8);
    float* w_p   = alloc(128);
    float* w_c   = alloc(128);
    float* cpc   = alloc(4);
    float* att1  = alloc((size_t)E*4);
    float* att2  = alloc((size_t)E*4);
    unsigned* emax_c = (unsigned*)alloc((size_t)NCLS*4);
    unsigned* emax_p = (unsigned*)alloc((size_t)NPROT*4);
    float* den_c = alloc((size_t)NCLS*4);
    float* den_p = alloc((size_t)NPROT*4);
    float* acc_c = alloc((size_t)NCLS*128);        // SAGE acc, reused as GAT acc_gc
    float* acc_p = alloc((size_t)NPROT*128);       // SAGE acc, reused as GAT acc_gp
    int* deg_c = (int*)alloc(NCLS);
    int* deg_p = (int*)alloc(NPROT);
    float* u_p = alloc(NPROT);
    float* u_c = alloc(NCLS);
    if(off*4 > ws_size) return;   // workspace too small -> bail (validation will flag)

    // --- zero init ---
    hipMemsetAsync(acc_c, 0, (size_t)NCLS*128*4, stream);
    hipMemsetAsync(acc_p, 0, (size_t)NPROT*128*4, stream);
    hipMemsetAsync(deg_c, 0, (size_t)NCLS*4, stream);
    hipMemsetAsync(deg_p, 0, (size_t)NPROT*4, stream);

    // --- weight prep ---
    build_cat<<<(DIMP*256+255)/256,256,0,stream>>>(sage_pc_Wl, sage_cp_Wr, Wcat1, DIMP);
    build_cat<<<(DIMC*256+255)/256,256,0,stream>>>(sage_cp_Wl, sage_pc_Wr, WcatC, DIMC);
    fold_att<<<2,256,0,stream>>>(gat_pc_Wsrc, gat_pc_asrc, projP, 0);
    fold_att<<<2,256,0,stream>>>(gat_cp_Wdst, gat_cp_adst, projP, 4);
    fold_att<<<2,256,0,stream>>>(gat_pc_Wdst, gat_pc_adst, projC, 0);
    fold_att<<<2,256,0,stream>>>(gat_cp_Wsrc, gat_cp_asrc, projC, 4);
    fold_link<<<1,256,0,stream>>>(lin_p_W, lin_p_b, lin_c_W, lin_c_b, link_W, w_p, w_c, cpc);

    // --- layer 1: fused feature GEMMs + SAGE ---
    gemm64<<<dim3(4,(NPROT+63)/64),256,0,stream>>>(x_p, Wcat1, P1, NPROT, 256, DIMP);
    gemm64<<<dim3(4,(NCLS +63)/64),256,0,stream>>>(x_c, WcatC, C1, NCLS, 256, DIMC);
    deg_kernel<<<(E+255)/256,256,0,stream>>>(src,dst,deg_p,deg_c,E);
    sage_agg<<<E,256,0,stream>>>(src,dst,P1,C1,acc_c,acc_p);
    build_h<<<((size_t)NCLS*128+255)/256,256,0,stream>>>(acc_c, deg_c, C1, sage_pc_bl, h_c, NCLS);
    build_h<<<((size_t)NPROT*128+255)/256,256,0,stream>>>(acc_p, deg_p, P1, sage_cp_bl, h_p, NPROT);

    // --- layer 2: GAT ---
    gemm64<<<dim3(8,(NPROT+63)/64),256,0,stream>>>(h_p, gat_pc_Wsrc, hs_p, NPROT, 512, 128);
    gemm64<<<dim3(8,(NCLS +63)/64),256,0,stream>>>(h_c, gat_cp_Wsrc, hs_c, NCLS, 512, 128);
    gemm_n8<<<(NPROT+31)/32,256,0,stream>>>(h_p, projP, attP, NPROT);
    gemm_n8<<<(NCLS +31)/32,256,0,stream>>>(h_c, projC, attC, NCLS);

    hipMemsetAsync(emax_c, 0, (size_t)NCLS*4*4, stream);
    hipMemsetAsync(emax_p, 0, (size_t)NPROT*4*4, stream);
    hipMemsetAsync(den_c, 0, (size_t)NCLS*4*4, stream);
    hipMemsetAsync(den_p, 0, (size_t)NPROT*4*4, stream);
    hipMemsetAsync(acc_c, 0, (size_t)NCLS*128*4, stream);   // now acc_gc
    hipMemsetAsync(acc_p, 0, (size_t)NPROT*128*4, stream);  // now acc_gp

    att_max<<<((size_t)E*4+255)/256,256,0,stream>>>(src,dst,attP,attC,att1,att2,emax_c,emax_p,E);
    att_exp<<<((size_t)E*4+255)/256,256,0,stream>>>(src,dst,att1,att2,emax_c,emax_p,den_c,den_p,E);
    gat_agg<<<E,256,0,stream>>>(src,dst,att1,att2,den_c,den_p,hs_p,hs_c,acc_c,acc_p);

    // --- output head (lin + link folded) ---
    node_u<<<(NCLS +3)/4,256,0,stream>>>(acc_c, gat_pc_b, w_c, cpc, 1, u_c, NCLS);
    node_u<<<(NPROT+3)/4,256,0,stream>>>(acc_p, gat_cp_b, w_p, cpc, 0, u_p, NPROT);
    link_out<<<(EL+255)/256,256,0,stream>>>(els, eld, u_p, u_c, link_b, (float*)d_out, EL);
}

// Round 2
// 852.807 us; speedup vs baseline: 1.4467x; 1.4467x over previous
//
#include <hip/hip_runtime.h>
#include <math.h>

#define NPROT 50000
#define NCLS  5000
#define DIMP  1280
#define DIMC  256

typedef float4 f4;
typedef __attribute__((ext_vector_type(8))) short short8;
typedef __attribute__((ext_vector_type(4))) float f32x4;

// ---------- helpers ----------
__device__ __forceinline__ unsigned encf(float x){
    unsigned u = __float_as_uint(x);
    return (u & 0x80000000u) ? ~u : (u | 0x80000000u);
}
__device__ __forceinline__ float decf(unsigned u){
    return __uint_as_float((u & 0x80000000u) ? (u & 0x7FFFFFFFu) : ~u);
}
__device__ __forceinline__ void atomAddF(float* p, float v){
    unsafeAtomicAdd(p, v);
}
__device__ __forceinline__ unsigned short f2bf(float f){   // round-to-nearest-even
    unsigned u = __float_as_uint(f);
    u += 0x7FFFu + ((u >> 16) & 1u);
    return (unsigned short)(u >> 16);
}
__device__ __forceinline__ float bf2f(unsigned short b){
    return __uint_as_float(((unsigned)b) << 16);
}
__device__ __forceinline__ void gload_lds16(const void* g, void* l){
    __builtin_amdgcn_global_load_lds((const __attribute__((address_space(1))) void*)g,
                                     (__attribute__((address_space(3))) void*)l, 16, 0, 0);
}

// ---------- bf16 MFMA GEMM: C[M,N] = A[M,K] @ Bt[N,K]^T  (C f32) ----------
// AF32: A is f32 in global (staged f32, converted to bf16 at frag load).
// else: A is bf16. Bt always bf16 [N][K] row-major. N%128==0, K%32==0.
template<bool AF32>
__global__ __launch_bounds__(256) void gemm_mfma(const float* __restrict__ Af,
                                                 const unsigned short* __restrict__ Ab,
                                                 const unsigned short* __restrict__ Bt,
                                                 float* __restrict__ C,
                                                 int M, int N, int K){
    constexpr int ABYTES = AF32 ? 4 : 2;
    __shared__ __align__(16) unsigned char As[128*32*ABYTES];
    __shared__ __align__(16) unsigned char Bs[128*32*2];
    const int tid  = threadIdx.x;
    const int lane = tid & 63;
    const int w    = tid >> 6;
    const int wm   = w >> 1, wn = w & 1;
    const int row0 = blockIdx.y * 128;
    const int col0 = blockIdx.x * 128;

    f32x4 acc[4][4] = {};

    const int kg = lane >> 4;    // 0..3 (k-group of 8)
    const int fr = lane & 15;

    for(int k0 = 0; k0 < K; k0 += 32){
        // ---- stage A (swizzled source -> linear LDS) ----
        if constexpr (AF32){
            // 1024 x 16B chunks, 8 per 128B row; swz: scc = cc ^ (r&7)
            #pragma unroll
            for(int i=0;i<4;i++){
                int c  = w*256 + i*64 + lane;
                int r  = c >> 3;
                int cc = c & 7;
                int scc = cc ^ (r & 7);
                int srow = min(row0 + r, M-1);
                const void* g = (const void*)(Af + (size_t)srow*K + k0 + scc*4);
                void* l = (void*)(As + (w*256 + i*64)*16);
                gload_lds16(g, l);
            }
        } else {
            // 512 x 16B chunks, 4 per 64B row; swz: scc = cc ^ ((r>>1)&3)
            #pragma unroll
            for(int i=0;i<2;i++){
                int c  = w*128 + i*64 + lane;
                int r  = c >> 2;
                int cc = c & 3;
                int scc = cc ^ ((r>>1) & 3);
                int srow = min(row0 + r, M-1);
                const void* g = (const void*)(Ab + (size_t)srow*K + k0 + scc*8);
                void* l = (void*)(As + (w*128 + i*64)*16);
                gload_lds16(g, l);
            }
        }
        // ---- stage B (bf16, 512 chunks, 4 per 64B row) ----
        #pragma unroll
        for(int i=0;i<2;i++){
            int c  = w*128 + i*64 + lane;
            int r  = c >> 2;
            int cc = c & 3;
            int scc = cc ^ ((r>>1) & 3);
            const void* g = (const void*)(Bt + (size_t)(col0 + r)*K + k0 + scc*8);
            void* l = (void*)(Bs + (w*128 + i*64)*16);
            gload_lds16(g, l);
        }
        __syncthreads();

        // ---- fragments ----
        short8 aF[4], bF[4];
        #pragma unroll
        for(int m=0;m<4;m++){
            int r = wm*64 + m*16 + fr;
            if constexpr (AF32){
                int b0 = r*128 + kg*32;
                f4 lo = *(const f4*)(As + (( b0      ) ^ ((r&7)<<4)));
                f4 hi = *(const f4*)(As + (( b0 + 16 ) ^ ((r&7)<<4)));
                union { short8 s; unsigned short u[8]; } uu;
                uu.u[0]=f2bf(lo.x); uu.u[1]=f2bf(lo.y); uu.u[2]=f2bf(lo.z); uu.u[3]=f2bf(lo.w);
                uu.u[4]=f2bf(hi.x); uu.u[5]=f2bf(hi.y); uu.u[6]=f2bf(hi.z); uu.u[7]=f2bf(hi.w);
                aF[m] = uu.s;
            } else {
                int b0 = (r*64 + kg*16) ^ (((r>>1)&3)<<4);
                aF[m] = *(const short8*)(As + b0);
            }
        }
        #pragma unroll
        for(int n=0;n<4;n++){
            int r = wn*64 + n*16 + fr;
            int b0 = (r*64 + kg*16) ^ (((r>>1)&3)<<4);
            bF[n] = *(const short8*)(Bs + b0);
        }
        #pragma unroll
        for(int m=0;m<4;m++)
        #pragma unroll
        for(int n=0;n<4;n++)
            acc[m][n] = __builtin_amdgcn_mfma_f32_16x16x32_bf16(aF[m], bF[n], acc[m][n], 0, 0, 0);
        __syncthreads();
    }

    // ---- write C: col = lane&15, row = (lane>>4)*4 + reg ----
    #pragma unroll
    for(int m=0;m<4;m++){
        #pragma unroll
        for(int r=0;r<4;r++){
            int row = row0 + wm*64 + m*16 + kg*4 + r;
            if(row < M){
                #pragma unroll
                for(int n=0;n<4;n++){
                    C[(size_t)row*N + col0 + wn*64 + n*16 + fr] = acc[m][n][r];
                }
            }
        }
    }
}

// ---------- f32 tiled GEMM (kept for the small class-side GEMM) ----------
__global__ __launch_bounds__(256) void gemm64(const float* __restrict__ A,
                                              const float* __restrict__ B,
                                              float* __restrict__ C,
                                              int M, int N, int K){
    __shared__ __align__(16) float As[16][68];
    __shared__ __align__(16) float Bs[16][64];
    const int tid = threadIdx.x;
    const int row0 = blockIdx.y * 64;
    const int col0 = blockIdx.x * 64;
    const int ty = tid >> 4;
    const int tx = tid & 15;
    const int m  = tid >> 2;
    const int kq = (tid & 3) << 2;
    const int kb = tid >> 4;
    const int c4 = (tid & 15) << 2;

    float acc[4][4];
#pragma unroll
    for(int i=0;i<4;i++)
#pragma unroll
        for(int j=0;j<4;j++) acc[i][j]=0.f;

    const bool arow_ok = (row0 + m) < M;
    const float* Abase = A + (size_t)(row0 + m) * K + kq;
    const float* Bbase = B + col0 + c4 + (size_t)kb * N;

    for(int k0 = 0; k0 < K; k0 += 16){
        f4 av;
        if(arow_ok) av = *(const f4*)(Abase + k0);
        else        av = make_float4(0.f,0.f,0.f,0.f);
        As[kq+0][m]=av.x; As[kq+1][m]=av.y; As[kq+2][m]=av.z; As[kq+3][m]=av.w;
        *(f4*)&Bs[kb][c4] = *(const f4*)(Bbase + (size_t)k0 * N);
        __syncthreads();
#pragma unroll
        for(int kk=0;kk<16;kk++){
            f4 a = *(const f4*)&As[kk][ty<<2];
            f4 b = *(const f4*)&Bs[kk][tx<<2];
            float ar[4]={a.x,a.y,a.z,a.w};
            float br[4]={b.x,b.y,b.z,b.w};
#pragma unroll
            for(int i=0;i<4;i++)
#pragma unroll
                for(int j=0;j<4;j++) acc[i][j] += ar[i]*br[j];
        }
        __syncthreads();
    }
#pragma unroll
    for(int i=0;i<4;i++){
        int r = row0 + (ty<<2) + i;
        if(r < M){
            f4 v = make_float4(acc[i][0],acc[i][1],acc[i][2],acc[i][3]);
            *(f4*)&C[(size_t)r*N + col0 + (tx<<2)] = v;
        }
    }
}

// ---------- narrow GEMM: C[M,8] = A_bf16[M,128] @ B[128,8] ----------
__global__ __launch_bounds__(256) void gemm_n8(const unsigned short* __restrict__ A,
                                               const float* __restrict__ B8,
                                               float* __restrict__ C, int M){
    __shared__ float Bs[128*8];
    const int tid = threadIdx.x;
    for(int i=tid;i<1024;i+=256) Bs[i]=B8[i];
    __syncthreads();
    const int row = blockIdx.x*32 + (tid>>3);
    const int j = tid & 7;
    if(row >= M) return;
    const unsigned short* a = A + (size_t)row*128;
    float s=0.f;
#pragma unroll
    for(int k=0;k<128;k++) s += bf2f(a[k])*Bs[k*8+j];
    C[(size_t)row*8+j]=s;
}

// ---------- weight prep ----------
__global__ void build_cat(const float* __restrict__ Wa, const float* __restrict__ Wb,
                          float* __restrict__ out, int K){
    int t = blockIdx.x*256 + threadIdx.x;
    if(t >= K*256) return;
    int k = t >> 8, j = t & 255;
    out[t] = (j<128) ? Wa[k*128+j] : Wb[k*128 + (j-128)];
}

// BtP[n][k] (bf16, [256][1280]) = n<128 ? Wl[k][n] : Wr[k][n-128]
__global__ void build_btP(const float* __restrict__ Wl, const float* __restrict__ Wr,
                          unsigned short* __restrict__ Bt){
    int t = blockIdx.x*256 + threadIdx.x;
    if(t >= 256*DIMP) return;
    int n = t / DIMP, k = t % DIMP;
    float v = (n<128) ? Wl[(size_t)k*128 + n] : Wr[(size_t)k*128 + (n-128)];
    Bt[t] = f2bf(v);
}

// Bt[n][k] (bf16, [512][128]) = W[k][n]   (W: [128,512])
__global__ void build_btS(const float* __restrict__ W, unsigned short* __restrict__ Bt){
    int t = blockIdx.x*256 + threadIdx.x;
    if(t >= 512*128) return;
    int n = t >> 7, k = t & 127;
    Bt[t] = f2bf(W[(size_t)k*512 + n]);
}

// proj[k][colbase+h] = sum_c W[k, h*128+c] * a[h,c]
__global__ void fold_att(const float* __restrict__ W, const float* __restrict__ a,
                         float* __restrict__ proj, int colbase){
    int t = blockIdx.x*256 + threadIdx.x;
    if(t >= 512) return;
    int k = t >> 2, h = t & 3;
    const float* w = W + (size_t)k*512 + h*128;
    const float* av = a + h*128;
    float s=0.f;
    for(int c=0;c<128;c++) s += w[c]*av[c];
    proj[k*8 + colbase + h] = s;
}

__global__ void fold_link(const float* __restrict__ lpW, const float* __restrict__ lpb,
                          const float* __restrict__ lcW, const float* __restrict__ lcb,
                          const float* __restrict__ linkW,
                          float* __restrict__ w_p, float* __restrict__ w_c,
                          float* __restrict__ cpc){
    int t = threadIdx.x;
    if(t < 128){
        float s=0.f;
        for(int o=0;o<128;o++) s += lpW[t*128+o]*linkW[o];
        w_p[t]=s;
    } else {
        int j=t-128;
        float s=0.f;
        for(int o=0;o<128;o++) s += lcW[j*128+o]*linkW[128+o];
        w_c[j]=s;
    }
    if(t==0){ float s=0.f; for(int o=0;o<128;o++) s+=lpb[o]*linkW[o];      cpc[0]=s; }
    if(t==1){ float s=0.f; for(int o=0;o<128;o++) s+=lcb[o]*linkW[128+o];  cpc[1]=s; }
}

// ---------- edge kernels ----------
__global__ void deg_kernel(const int* __restrict__ src, const int* __restrict__ dst,
                           int* __restrict__ deg_p, int* __restrict__ deg_c, int E){
    int e = blockIdx.x*256 + threadIdx.x;
    if(e>=E) return;
    atomicAdd(&deg_p[src[e]],1);
    atomicAdd(&deg_c[dst[e]],1);
}

__global__ __launch_bounds__(256) void sage_agg(const int* __restrict__ src, const int* __restrict__ dst,
                                                const float* __restrict__ P1, const float* __restrict__ C1,
                                                float* __restrict__ acc_c, float* __restrict__ acc_p){
    int e = blockIdx.x;
    int s = src[e], d = dst[e];
    int j = threadIdx.x;
    if(j < 128){
        atomAddF(&acc_c[(size_t)d*128+j], P1[(size_t)s*256+j]);
    } else {
        int j2 = j-128;
        atomAddF(&acc_p[(size_t)s*128+j2], C1[(size_t)d*256+j2]);
    }
}

// h(bf16) = relu(acc/max(deg,1) + bl + self[:,128:256])
__global__ void build_h(const float* __restrict__ acc, const int* __restrict__ deg,
                        const float* __restrict__ self, const float* __restrict__ bl,
                        unsigned short* __restrict__ h, int Nnode){
    int t = blockIdx.x*256 + threadIdx.x;
    if(t >= Nnode*128) return;
    int n = t >> 7, j = t & 127;
    float cnt = (float)max(deg[n],1);
    float v = acc[t]/cnt + bl[j] + self[(size_t)n*256 + 128 + j];
    h[t] = f2bf(fmaxf(v, 0.f));
}

__global__ void att_max(const int* __restrict__ src, const int* __restrict__ dst,
                        const float* __restrict__ attP, const float* __restrict__ attC,
                        float* __restrict__ att1, float* __restrict__ att2,
                        unsigned* __restrict__ emax_c, unsigned* __restrict__ emax_p, int E){
    int t = blockIdx.x*256 + threadIdx.x;
    if(t >= E*4) return;
    int e = t >> 2, h = t & 3;
    int s = src[e], d = dst[e];
    float e1 = attP[s*8+h]   + attC[d*8+h];
    e1 = e1 > 0.f ? e1 : 0.2f*e1;
    float e2 = attC[d*8+4+h] + attP[s*8+4+h];
    e2 = e2 > 0.f ? e2 : 0.2f*e2;
    att1[t] = e1;  att2[t] = e2;
    atomicMax(&emax_c[d*4+h], encf(e1));
    atomicMax(&emax_p[s*4+h], encf(e2));
}

__global__ void att_exp(const int* __restrict__ src, const int* __restrict__ dst,
                        float* __restrict__ att1, float* __restrict__ att2,
                        const unsigned* __restrict__ emax_c, const unsigned* __restrict__ emax_p,
                        float* __restrict__ den_c, float* __restrict__ den_p, int E){
    int t = blockIdx.x*256 + threadIdx.x;
    if(t >= E*4) return;
    int e = t >> 2, h = t & 3;
    int s = src[e], d = dst[e];
    float ee1 = expf(att1[t] - decf(emax_c[d*4+h]));
    float ee2 = expf(att2[t] - decf(emax_p[s*4+h]));
    att1[t]=ee1; att2[t]=ee2;
    atomAddF(&den_c[d*4+h], ee1);
    atomAddF(&den_p[s*4+h], ee2);
}

__global__ __launch_bounds__(256) void gat_agg(const int* __restrict__ src, const int* __restrict__ dst,
                                               const float* __restrict__ att1, const float* __restrict__ att2,
                                               const float* __restrict__ den_c, const float* __restrict__ den_p,
                                               const float* __restrict__ hs_p, const float* __restrict__ hs_c,
                                               float* __restrict__ acc_gc, float* __restrict__ acc_gp){
    __shared__ float al[8];
    int e = blockIdx.x;
    int s = src[e], d = dst[e];
    int tid = threadIdx.x;
    if(tid < 4)      al[tid]   = att1[e*4+tid]   / den_c[d*4+tid];
    else if(tid < 8) al[tid]   = att2[e*4+tid-4] / den_p[s*4+tid-4];
    __syncthreads();
    if(tid < 128){
        float sum = 0.f;
#pragma unroll
        for(int h=0;h<4;h++) sum += al[h]*hs_p[(size_t)s*512 + h*128 + tid];
        atomAddF(&acc_gc[(size_t)d*128 + tid], 0.25f*sum);
    } else {
        int j = tid - 128;
        float sum = 0.f;
#pragma unroll
        for(int h=0;h<4;h++) sum += al[4+h]*hs_c[(size_t)d*512 + h*128 + j];
        atomAddF(&acc_gp[(size_t)s*128 + j], 0.25f*sum);
    }
}

__global__ __launch_bounds__(256) void node_u(const float* __restrict__ acc, const float* __restrict__ b,
                                              const float* __restrict__ w, const float* __restrict__ cpc, int cidx,
                                              float* __restrict__ u, int Nnode){
    int tid = threadIdx.x;
    int node = blockIdx.x*4 + (tid>>6);
    int lane = tid & 63;
    if(node >= Nnode) return;
    int j = lane*2;
    float2 v = *(const float2*)&acc[(size_t)node*128 + j];
    float p = fmaxf(v.x + b[j],   0.f)*w[j]
            + fmaxf(v.y + b[j+1], 0.f)*w[j+1];
#pragma unroll
    for(int off=32; off; off>>=1) p += __shfl_down(p, off);
    if(lane==0) u[node] = p + cpc[cidx];
}

__global__ void link_out(const int* __restrict__ els, const int* __restrict__ eld,
                         const float* __restrict__ u_p, const float* __restrict__ u_c,
                         const float* __restrict__ linkb, float* __restrict__ out, int EL){
    int i = blockIdx.x*256 + threadIdx.x;
    if(i >= EL) return;
    float x = u_p[els[i]] + u_c[eld[i]] + linkb[0];
    out[i] = 1.f/(1.f + expf(-x));
}

// ---------- host ----------
extern "C" void kernel_launch(void* const* d_in, const int* in_sizes, int n_in,
                              void* d_out, int out_size, void* d_ws, size_t ws_size,
                              hipStream_t stream){
    const float* x_p  = (const float*)d_in[0];
    const float* x_c  = (const float*)d_in[1];
    const int*   src  = (const int*)d_in[2];
    const int*   dst  = (const int*)d_in[3];
    const int*   els  = (const int*)d_in[4];
    const int*   eld  = (const int*)d_in[5];
    const float* sage_pc_Wl = (const float*)d_in[6];
    const float* sage_pc_bl = (const float*)d_in[7];
    const float* sage_pc_Wr = (const float*)d_in[8];
    const float* sage_cp_Wl = (const float*)d_in[9];
    const float* sage_cp_bl = (const float*)d_in[10];
    const float* sage_cp_Wr = (const float*)d_in[11];
    const float* gat_pc_Wsrc = (const float*)d_in[12];
    const float* gat_pc_Wdst = (const float*)d_in[13];
    const float* gat_pc_asrc = (const float*)d_in[14];
    const float* gat_pc_adst = (const float*)d_in[15];
    const float* gat_pc_b    = (const float*)d_in[16];
    const float* gat_cp_Wsrc = (const float*)d_in[17];
    const float* gat_cp_Wdst = (const float*)d_in[18];
    const float* gat_cp_asrc = (const float*)d_in[19];
    const float* gat_cp_adst = (const float*)d_in[20];
    const float* gat_cp_b    = (const float*)d_in[21];
    const float* lin_p_W = (const float*)d_in[22];
    const float* lin_p_b = (const float*)d_in[23];
    const float* lin_c_W = (const float*)d_in[24];
    const float* lin_c_b = (const float*)d_in[25];
    const float* link_W  = (const float*)d_in[26];
    const float* link_b  = (const float*)d_in[27];

    const int E  = in_sizes[2];
    const int EL = in_sizes[4];

    float* ws = (float*)d_ws;
    size_t off = 0;
    auto alloc = [&](size_t n)->float*{ float* p = ws + off; off += (n + 3) & ~(size_t)3; return p; };

    unsigned short* BtP  = (unsigned short*)alloc((size_t)256*DIMP/2);  // bf16 [256][1280]
    float* WcatC = alloc((size_t)DIMC*256);                             // f32 [256][256]
    unsigned short* BtSp = (unsigned short*)alloc((size_t)512*128/2);   // bf16 [512][128]
    unsigned short* BtSc = (unsigned short*)alloc((size_t)512*128/2);
    float* P1    = alloc((size_t)NPROT*256);
    float* C1    = alloc((size_t)NCLS*256);
    unsigned short* h_p = (unsigned short*)alloc((size_t)NPROT*128/2);  // bf16
    unsigned short* h_c = (unsigned short*)alloc((size_t)NCLS*128/2);
    float* hs_p  = alloc((size_t)NPROT*512);
    float* hs_c  = alloc((size_t)NCLS*512);
    float* attP  = alloc((size_t)NPROT*8);
    float* attC  = alloc((size_t)NCLS*8);
    float* projP = alloc(128*8);
    float* projC = alloc(128*8);
    float* w_p   = alloc(128);
    float* w_c   = alloc(128);
    float* cpc   = alloc(4);
    float* att1  = alloc((size_t)E*4);
    float* att2  = alloc((size_t)E*4);
    unsigned* emax_c = (unsigned*)alloc((size_t)NCLS*4);
    unsigned* emax_p = (unsigned*)alloc((size_t)NPROT*4);
    float* den_c = alloc((size_t)NCLS*4);
    float* den_p = alloc((size_t)NPROT*4);
    float* acc_c = alloc((size_t)NCLS*128);
    float* acc_p = alloc((size_t)NPROT*128);
    int* deg_c = (int*)alloc(NCLS);
    int* deg_p = (int*)alloc(NPROT);
    float* u_p = alloc(NPROT);
    float* u_c = alloc(NCLS);
    if(off*4 > ws_size) return;

    // --- zero init ---
    hipMemsetAsync(acc_c, 0, (size_t)NCLS*128*4, stream);
    hipMemsetAsync(acc_p, 0, (size_t)NPROT*128*4, stream);
    hipMemsetAsync(deg_c, 0, (size_t)NCLS*4, stream);
    hipMemsetAsync(deg_p, 0, (size_t)NPROT*4, stream);

    // --- weight prep ---
    build_btP<<<(256*DIMP+255)/256,256,0,stream>>>(sage_pc_Wl, sage_cp_Wr, BtP);
    build_cat<<<(DIMC*256+255)/256,256,0,stream>>>(sage_cp_Wl, sage_pc_Wr, WcatC, DIMC);
    build_btS<<<(512*128+255)/256,256,0,stream>>>(gat_pc_Wsrc, BtSp);
    build_btS<<<(512*128+255)/256,256,0,stream>>>(gat_cp_Wsrc, BtSc);
    fold_att<<<2,256,0,stream>>>(gat_pc_Wsrc, gat_pc_asrc, projP, 0);
    fold_att<<<2,256,0,stream>>>(gat_cp_Wdst, gat_cp_adst, projP, 4);
    fold_att<<<2,256,0,stream>>>(gat_pc_Wdst, gat_pc_adst, projC, 0);
    fold_att<<<2,256,0,stream>>>(gat_cp_Wsrc, gat_cp_asrc, projC, 4);
    fold_link<<<1,256,0,stream>>>(lin_p_W, lin_p_b, lin_c_W, lin_c_b, link_W, w_p, w_c, cpc);

    // --- layer 1: P1 = x_p @ [Wl_pc | Wr_cp]  (MFMA, A f32-staged) ---
    gemm_mfma<true><<<dim3(2,(NPROT+127)/128),256,0,stream>>>(x_p, nullptr, BtP, P1, NPROT, 256, DIMP);
    gemm64<<<dim3(4,(NCLS+63)/64),256,0,stream>>>(x_c, WcatC, C1, NCLS, 256, DIMC);
    deg_kernel<<<(E+255)/256,256,0,stream>>>(src,dst,deg_p,deg_c,E);
    sage_agg<<<E,256,0,stream>>>(src,dst,P1,C1,acc_c,acc_p);
    build_h<<<((size_t)NCLS*128+255)/256,256,0,stream>>>(acc_c, deg_c, C1, sage_pc_bl, h_c, NCLS);
    build_h<<<((size_t)NPROT*128+255)/256,256,0,stream>>>(acc_p, deg_p, P1, sage_cp_bl, h_p, NPROT);

    // --- layer 2: hs = h @ Wsrc (MFMA, A bf16) ---
    gemm_mfma<false><<<dim3(4,(NPROT+127)/128),256,0,stream>>>(nullptr, h_p, BtSp, hs_p, NPROT, 512, 128);
    gemm_mfma<false><<<dim3(4,(NCLS +127)/128),256,0,stream>>>(nullptr, h_c, BtSc, hs_c, NCLS, 512, 128);
    gemm_n8<<<(NPROT+31)/32,256,0,stream>>>(h_p, projP, attP, NPROT);
    gemm_n8<<<(NCLS +31)/32,256,0,stream>>>(h_c, projC, attC, NCLS);

    hipMemsetAsync(emax_c, 0, (size_t)NCLS*4*4, stream);
    hipMemsetAsync(emax_p, 0, (size_t)NPROT*4*4, stream);
    hipMemsetAsync(den_c, 0, (size_t)NCLS*4*4, stream);
    hipMemsetAsync(den_p, 0, (size_t)NPROT*4*4, stream);
    hipMemsetAsync(acc_c, 0, (size_t)NCLS*128*4, stream);
    hipMemsetAsync(acc_p, 0, (size_t)NPROT*128*4, stream);

    att_max<<<((size_t)E*4+255)/256,256,0,stream>>>(src,dst,attP,attC,att1,att2,emax_c,emax_p,E);
    att_exp<<<((size_t)E*4+255)/256,256,0,stream>>>(src,dst,att1,att2,emax_c,emax_p,den_c,den_p,E);
    gat_agg<<<E,256,0,stream>>>(src,dst,att1,att2,den_c,den_p,hs_p,hs_c,acc_c,acc_p);

    node_u<<<(NCLS +3)/4,256,0,stream>>>(acc_c, gat_pc_b, w_c, cpc, 1, u_c, NCLS);
    node_u<<<(NPROT+3)/4,256,0,stream>>>(acc_p, gat_cp_b, w_p, cpc, 0, u_p, NPROT);
    link_out<<<(EL+255)/256,256,0,stream>>>(els, eld, u_p, u_c, link_b, (float*)d_out, EL);
}

// Round 3
// 530.315 us; speedup vs baseline: 2.3264x; 1.6081x over previous
//
#include <hip/hip_runtime.h>
#include <math.h>

#define NPROT 50000
#define NCLS  5000
#define DIMP  1280
#define DIMC  256

typedef float4 f4;
typedef __attribute__((ext_vector_type(8))) short short8;
typedef __attribute__((ext_vector_type(4))) float f32x4;

// ---------- helpers ----------
__device__ __forceinline__ unsigned short f2bf(float f){   // round-to-nearest-even
    unsigned u = __float_as_uint(f);
    u += 0x7FFFu + ((u >> 16) & 1u);
    return (unsigned short)(u >> 16);
}
__device__ __forceinline__ float bf2f(unsigned short b){
    return __uint_as_float(((unsigned)b) << 16);
}
__device__ __forceinline__ void gload_lds16(const void* g, void* l){
    __builtin_amdgcn_global_load_lds((const __attribute__((address_space(1))) void*)g,
                                     (__attribute__((address_space(3))) void*)l, 16, 0, 0);
}

// ---------- P1 GEMM: C_bf16[M,256] = A_f32[M,1280] @ Bt_bf16[256,1280]^T ----------
// 128x256 tile, 512 threads (8 waves of 64x64). A read exactly once.
__global__ __launch_bounds__(512) void gemm_p1(const float* __restrict__ Af,
                                               const unsigned short* __restrict__ Bt,
                                               unsigned short* __restrict__ C, int M){
    __shared__ __align__(16) unsigned char As[128*32*4];   // 16 KB f32
    __shared__ __align__(16) unsigned char Bs[256*32*2];   // 16 KB bf16
    const int tid  = threadIdx.x;
    const int lane = tid & 63;
    const int w    = tid >> 6;          // 0..7
    const int wm   = w >> 2, wn = w & 3;
    const int row0 = blockIdx.x * 128;
    const int kg = lane >> 4, fr = lane & 15;

    f32x4 acc[4][4] = {};

    for(int k0 = 0; k0 < DIMP; k0 += 32){
        // A: 1024 x 16B chunks (8 per 128B row), swz scc = cc ^ (r&7)
        #pragma unroll
        for(int i=0;i<2;i++){
            int c  = i*512 + w*64 + lane;
            int r  = c >> 3, cc = c & 7;
            int scc = cc ^ (r & 7);
            int srow = min(row0 + r, M-1);
            gload_lds16((const void*)(Af + (size_t)srow*DIMP + k0 + scc*4),
                        (void*)(As + (i*512 + w*64)*16));
        }
        // B: 1024 x 16B chunks (4 per 64B row), swz scc = cc ^ ((r>>1)&3)
        #pragma unroll
        for(int i=0;i<2;i++){
            int c  = i*512 + w*64 + lane;
            int r  = c >> 2, cc = c & 3;
            int scc = cc ^ ((r>>1) & 3);
            gload_lds16((const void*)(Bt + (size_t)r*DIMP + k0 + scc*8),
                        (void*)(Bs + (i*512 + w*64)*16));
        }
        __syncthreads();

        short8 aF[4], bF[4];
        #pragma unroll
        for(int m=0;m<4;m++){
            int r = wm*64 + m*16 + fr;
            int b0 = r*128 + kg*32;
            f4 lo = *(const f4*)(As + (( b0      ) ^ ((r&7)<<4)));
            f4 hi = *(const f4*)(As + (( b0 + 16 ) ^ ((r&7)<<4)));
            union { short8 s; unsigned short u[8]; } uu;
            uu.u[0]=f2bf(lo.x); uu.u[1]=f2bf(lo.y); uu.u[2]=f2bf(lo.z); uu.u[3]=f2bf(lo.w);
            uu.u[4]=f2bf(hi.x); uu.u[5]=f2bf(hi.y); uu.u[6]=f2bf(hi.z); uu.u[7]=f2bf(hi.w);
            aF[m] = uu.s;
        }
        #pragma unroll
        for(int n=0;n<4;n++){
            int r = wn*64 + n*16 + fr;
            int b0 = (r*64 + kg*16) ^ (((r>>1)&3)<<4);
            bF[n] = *(const short8*)(Bs + b0);
        }
        #pragma unroll
        for(int m=0;m<4;m++)
        #pragma unroll
        for(int n=0;n<4;n++)
            acc[m][n] = __builtin_amdgcn_mfma_f32_16x16x32_bf16(aF[m], bF[n], acc[m][n], 0, 0, 0);
        __syncthreads();
    }

    #pragma unroll
    for(int m=0;m<4;m++)
    #pragma unroll
    for(int r=0;r<4;r++){
        int row = row0 + wm*64 + m*16 + kg*4 + r;
        if(row < M){
            #pragma unroll
            for(int n=0;n<4;n++)
                C[(size_t)row*256 + wn*64 + n*16 + fr] = f2bf(acc[m][n][r]);
        }
    }
}

// ---------- hs GEMM: C_bf16[M,512] = A_bf16[M,128] @ Bt_bf16[512,128]^T ----------
// 128x128 tile, 256 threads (4 waves of 64x64). K=128 fixed.
__global__ __launch_bounds__(256) void gemm_hs(const unsigned short* __restrict__ A,
                                               const unsigned short* __restrict__ Bt,
                                               unsigned short* __restrict__ C, int M){
    __shared__ __align__(16) unsigned char As[128*32*2];
    __shared__ __align__(16) unsigned char Bs[128*32*2];
    const int tid  = threadIdx.x;
    const int lane = tid & 63;
    const int w    = tid >> 6;
    const int wm   = w >> 1, wn = w & 1;
    const int row0 = blockIdx.y * 128;
    const int col0 = blockIdx.x * 128;
    const int kg = lane >> 4, fr = lane & 15;

    f32x4 acc[4][4] = {};

    for(int k0 = 0; k0 < 128; k0 += 32){
        #pragma unroll
        for(int i=0;i<2;i++){
            int c  = i*256 + w*64 + lane;
            int r  = c >> 2, cc = c & 3;
            int scc = cc ^ ((r>>1) & 3);
            int srow = min(row0 + r, M-1);
            gload_lds16((const void*)(A + (size_t)srow*128 + k0 + scc*8),
                        (void*)(As + (i*256 + w*64)*16));
        }
        #pragma unroll
        for(int i=0;i<2;i++){
            int c  = i*256 + w*64 + lane;
            int r  = c >> 2, cc = c & 3;
            int scc = cc ^ ((r>>1) & 3);
            gload_lds16((const void*)(Bt + (size_t)(col0 + r)*128 + k0 + scc*8),
                        (void*)(Bs + (i*256 + w*64)*16));
        }
        __syncthreads();

        short8 aF[4], bF[4];
        #pragma unroll
        for(int m=0;m<4;m++){
            int r = wm*64 + m*16 + fr;
            int b0 = (r*64 + kg*16) ^ (((r>>1)&3)<<4);
            aF[m] = *(const short8*)(As + b0);
        }
        #pragma unroll
        for(int n=0;n<4;n++){
            int r = wn*64 + n*16 + fr;
            int b0 = (r*64 + kg*16) ^ (((r>>1)&3)<<4);
            bF[n] = *(const short8*)(Bs + b0);
        }
        #pragma unroll
        for(int m=0;m<4;m++)
        #pragma unroll
        for(int n=0;n<4;n++)
            acc[m][n] = __builtin_amdgcn_mfma_f32_16x16x32_bf16(aF[m], bF[n], acc[m][n], 0, 0, 0);
        __syncthreads();
    }

    #pragma unroll
    for(int m=0;m<4;m++)
    #pragma unroll
    for(int r=0;r<4;r++){
        int row = row0 + wm*64 + m*16 + kg*4 + r;
        if(row < M){
            #pragma unroll
            for(int n=0;n<4;n++)
                C[(size_t)row*512 + col0 + wn*64 + n*16 + fr] = f2bf(acc[m][n][r]);
        }
    }
}

// ---------- f32 tiled GEMM (class-side C1) ----------
__global__ __launch_bounds__(256) void gemm64(const float* __restrict__ A,
                                              const float* __restrict__ B,
                                              float* __restrict__ C,
                                              int M, int N, int K){
    __shared__ __align__(16) float As[16][68];
    __shared__ __align__(16) float Bs[16][64];
    const int tid = threadIdx.x;
    const int row0 = blockIdx.y * 64;
    const int col0 = blockIdx.x * 64;
    const int ty = tid >> 4;
    const int tx = tid & 15;
    const int m  = tid >> 2;
    const int kq = (tid & 3) << 2;
    const int kb = tid >> 4;
    const int c4 = (tid & 15) << 2;

    float acc[4][4];
#pragma unroll
    for(int i=0;i<4;i++)
#pragma unroll
        for(int j=0;j<4;j++) acc[i][j]=0.f;

    const bool arow_ok = (row0 + m) < M;
    const float* Abase = A + (size_t)(row0 + m) * K + kq;
    const float* Bbase = B + col0 + c4 + (size_t)kb * N;

    for(int k0 = 0; k0 < K; k0 += 16){
        f4 av;
        if(arow_ok) av = *(const f4*)(Abase + k0);
        else        av = make_float4(0.f,0.f,0.f,0.f);
        As[kq+0][m]=av.x; As[kq+1][m]=av.y; As[kq+2][m]=av.z; As[kq+3][m]=av.w;
        *(f4*)&Bs[kb][c4] = *(const f4*)(Bbase + (size_t)k0 * N);
        __syncthreads();
#pragma unroll
        for(int kk=0;kk<16;kk++){
            f4 a = *(const f4*)&As[kk][ty<<2];
            f4 b = *(const f4*)&Bs[kk][tx<<2];
            float ar[4]={a.x,a.y,a.z,a.w};
            float br[4]={b.x,b.y,b.z,b.w};
#pragma unroll
            for(int i=0;i<4;i++)
#pragma unroll
                for(int j=0;j<4;j++) acc[i][j] += ar[i]*br[j];
        }
        __syncthreads();
    }
#pragma unroll
    for(int i=0;i<4;i++){
        int r = row0 + (ty<<2) + i;
        if(r < M){
            f4 v = make_float4(acc[i][0],acc[i][1],acc[i][2],acc[i][3]);
            *(f4*)&C[(size_t)r*N + col0 + (tx<<2)] = v;
        }
    }
}

// ---------- narrow GEMM: C[M,8] = A_bf16[M,128] @ B[128,8] ----------
__global__ __launch_bounds__(256) void gemm_n8(const unsigned short* __restrict__ A,
                                               const float* __restrict__ B8,
                                               float* __restrict__ C, int M){
    __shared__ float Bs[128*8];
    const int tid = threadIdx.x;
    for(int i=tid;i<1024;i+=256) Bs[i]=B8[i];
    __syncthreads();
    const int row = blockIdx.x*32 + (tid>>3);
    const int j = tid & 7;
    if(row >= M) return;
    const unsigned short* a = A + (size_t)row*128;
    float s=0.f;
#pragma unroll
    for(int k=0;k<128;k++) s += bf2f(a[k])*Bs[k*8+j];
    C[(size_t)row*8+j]=s;
}

// ---------- weight prep ----------
__global__ void build_cat(const float* __restrict__ Wa, const float* __restrict__ Wb,
                          float* __restrict__ out, int K){
    int t = blockIdx.x*256 + threadIdx.x;
    if(t >= K*256) return;
    int k = t >> 8, j = t & 255;
    out[t] = (j<128) ? Wa[k*128+j] : Wb[k*128 + (j-128)];
}

__global__ void build_btP(const float* __restrict__ Wl, const float* __restrict__ Wr,
                          unsigned short* __restrict__ Bt){
    int t = blockIdx.x*256 + threadIdx.x;
    if(t >= 256*DIMP) return;
    int n = t / DIMP, k = t % DIMP;
    float v = (n<128) ? Wl[(size_t)k*128 + n] : Wr[(size_t)k*128 + (n-128)];
    Bt[t] = f2bf(v);
}

__global__ void build_btS(const float* __restrict__ W, unsigned short* __restrict__ Bt){
    int t = blockIdx.x*256 + threadIdx.x;
    if(t >= 512*128) return;
    int n = t >> 7, k = t & 127;
    Bt[t] = f2bf(W[(size_t)k*512 + n]);
}

__global__ void fold_att(const float* __restrict__ W, const float* __restrict__ a,
                         float* __restrict__ proj, int colbase){
    int t = blockIdx.x*256 + threadIdx.x;
    if(t >= 512) return;
    int k = t >> 2, h = t & 3;
    const float* w = W + (size_t)k*512 + h*128;
    const float* av = a + h*128;
    float s=0.f;
    for(int c=0;c<128;c++) s += w[c]*av[c];
    proj[k*8 + colbase + h] = s;
}

__global__ void fold_link(const float* __restrict__ lpW, const float* __restrict__ lpb,
                          const float* __restrict__ lcW, const float* __restrict__ lcb,
                          const float* __restrict__ linkW,
                          float* __restrict__ w_p, float* __restrict__ w_c,
                          float* __restrict__ cpc){
    int t = threadIdx.x;
    if(t < 128){
        float s=0.f;
        for(int o=0;o<128;o++) s += lpW[t*128+o]*linkW[o];
        w_p[t]=s;
    } else {
        int j=t-128;
        float s=0.f;
        for(int o=0;o<128;o++) s += lcW[j*128+o]*linkW[128+o];
        w_c[j]=s;
    }
    if(t==0){ float s=0.f; for(int o=0;o<128;o++) s+=lpb[o]*linkW[o];      cpc[0]=s; }
    if(t==1){ float s=0.f; for(int o=0;o<128;o++) s+=lcb[o]*linkW[128+o];  cpc[1]=s; }
}

// ---------- CSR construction ----------
__global__ void deg_kernel(const int* __restrict__ src, const int* __restrict__ dst,
                           int* __restrict__ deg_p, int* __restrict__ deg_c, int E){
    int e = blockIdx.x*256 + threadIdx.x;
    if(e>=E) return;
    atomicAdd(&deg_p[src[e]],1);
    atomicAdd(&deg_c[dst[e]],1);
}

// single-block exclusive scan (n up to ~64k); out has n+1 entries
__global__ __launch_bounds__(1024) void scan_excl(const int* __restrict__ in,
                                                  int* __restrict__ out, int n){
    __shared__ int buf[1024];
    __shared__ int carry;
    int tid = threadIdx.x;
    if(tid==0) carry = 0;
    __syncthreads();
    for(int base=0; base<n; base+=1024){
        int v = (base+tid<n) ? in[base+tid] : 0;
        buf[tid] = v;
        __syncthreads();
        for(int o=1;o<1024;o<<=1){
            int t = (tid>=o) ? buf[tid-o] : 0;
            __syncthreads();
            buf[tid] += t;
            __syncthreads();
        }
        int c = carry;
        int total = buf[1023];
        if(base+tid<n) out[base+tid] = c + buf[tid] - v;
        __syncthreads();
        if(tid==0) carry = c + total;
        __syncthreads();
    }
    if(tid==0) out[n] = carry;
}

__global__ void csr_fill(const int* __restrict__ src, const int* __restrict__ dst,
                         const int* __restrict__ off_c, const int* __restrict__ off_p,
                         int* __restrict__ cur_c, int* __restrict__ cur_p,
                         int* __restrict__ adj_c, int* __restrict__ adj_p, int E){
    int e = blockIdx.x*256 + threadIdx.x;
    if(e>=E) return;
    int s = src[e], d = dst[e];
    int pc = atomicAdd(&cur_c[d],1); adj_c[off_c[d]+pc] = s;
    int pp = atomicAdd(&cur_p[s],1); adj_p[off_p[s]+pp] = d;
}

// ---------- SAGE: gather-mean + bias + self + relu -> h bf16 ----------
// GB=1: gather bf16 (P1), self f32 (C1).  GB=0: gather f32 (C1), self bf16 (P1).
template<int GB>
__global__ __launch_bounds__(256) void sage_csr(const int* __restrict__ off, const int* __restrict__ adj,
                                                const void* __restrict__ gsrc, const void* __restrict__ gself,
                                                const float* __restrict__ bl,
                                                unsigned short* __restrict__ h, int Nnode){
    int node = blockIdx.x*4 + (threadIdx.x>>6);
    int l = threadIdx.x & 63;
    if(node >= Nnode) return;
    int b = off[node], deg = off[node+1]-b;
    float a0=0.f, a1=0.f;
    for(int i=0;i<deg;i++){
        int s = adj[b+i];
        if constexpr (GB){
            ushort2 v = *((const ushort2*)gsrc + (size_t)s*128 + l);
            a0 += bf2f(v.x); a1 += bf2f(v.y);
        } else {
            float2 v = *((const float2*)gsrc + (size_t)s*128 + l);
            a0 += v.x; a1 += v.y;
        }
    }
    float inv = 1.f/(float)max(deg,1);
    float s0, s1;
    if constexpr (GB){
        float2 v = *((const float2*)gself + (size_t)node*128 + 64 + l);
        s0=v.x; s1=v.y;
    } else {
        ushort2 v = *((const ushort2*)gself + (size_t)node*128 + 64 + l);
        s0=bf2f(v.x); s1=bf2f(v.y);
    }
    float h0 = fmaxf(a0*inv + bl[2*l]   + s0, 0.f);
    float h1 = fmaxf(a1*inv + bl[2*l+1] + s1, 0.f);
    ushort2 o; o.x=f2bf(h0); o.y=f2bf(h1);
    *((ushort2*)h + (size_t)node*64 + l) = o;
}

// ---------- fused GAT + head-mean + relu + output-projection dot ----------
// one block (128 threads) per destination node; softmax without max-subtraction
// (logits are O(1): exact same math as reference's stabilized softmax).
__global__ __launch_bounds__(128) void gat_csr(const int* __restrict__ off, const int* __restrict__ adj,
                                               const float* __restrict__ attS, int sbase,
                                               const float* __restrict__ attD, int dbase,
                                               const unsigned short* __restrict__ hs,
                                               const float* __restrict__ gb, const float* __restrict__ wv,
                                               const float* __restrict__ cpc, int cidx,
                                               float* __restrict__ u, int Nnode){
    __shared__ float ald[4];
    __shared__ int   adjS[32];
    __shared__ float eeS[32*4];
    __shared__ float red[128];
    __shared__ float den4[4];
    __shared__ float ws2[2];

    int n = blockIdx.x;
    if(n >= Nnode) return;
    int j = threadIdx.x;
    int b = off[n], deg = off[n+1]-b;
    if(j < 4) ald[j] = attD[(size_t)n*8 + dbase + j];

    float acc0=0.f, acc1=0.f, acc2=0.f, acc3=0.f;
    float denP = 0.f;

    for(int base=0; base<deg; base+=32){
        int cnt = min(32, deg-base);
        if(j < cnt) adjS[j] = adj[b+base+j];
        __syncthreads();
        if(j < cnt*4){
            int i = j>>2, h = j&3;
            int s = adjS[i];
            float e = attS[(size_t)s*8 + sbase + h] + ald[h];
            e = e > 0.f ? e : 0.2f*e;
            float ee = __expf(e);
            eeS[j] = ee;
            denP += ee;
        }
        __syncthreads();
        for(int ii=0; ii<cnt; ii++){
            int s = adjS[ii];
            const unsigned short* row = hs + (size_t)s*512;
            float4 ee = *(const float4*)&eeS[ii*4];
            acc0 += ee.x * bf2f(row[j]);
            acc1 += ee.y * bf2f(row[128+j]);
            acc2 += ee.z * bf2f(row[256+j]);
            acc3 += ee.w * bf2f(row[384+j]);
        }
        __syncthreads();
    }

    // reduce per-head denominators (thread j only contributed to head j&3)
    red[j] = denP;
    __syncthreads();
    if(j < 4){
        float s = 0.f;
        for(int t=j; t<128; t+=4) s += red[t];
        den4[j] = s;
    }
    __syncthreads();

    float outj = 0.f;
    if(deg > 0)
        outj = 0.25f*(acc0/den4[0] + acc1/den4[1] + acc2/den4[2] + acc3/den4[3]);

    // epilogue: u[n] = sum_j relu(outj + gb[j]) * wv[j] + cpc[cidx]
    float val = fmaxf(outj + gb[j], 0.f) * wv[j];
    #pragma unroll
    for(int o=32;o;o>>=1) val += __shfl_down(val, o);
    if((j & 63) == 0) ws2[j>>6] = val;
    __syncthreads();
    if(j == 0) u[n] = ws2[0] + ws2[1] + cpc[cidx];
}

__global__ void link_out(const int* __restrict__ els, const int* __restrict__ eld,
                         const float* __restrict__ u_p, const float* __restrict__ u_c,
                         const float* __restrict__ linkb, float* __restrict__ out, int EL){
    int i = blockIdx.x*256 + threadIdx.x;
    if(i >= EL) return;
    float x = u_p[els[i]] + u_c[eld[i]] + linkb[0];
    out[i] = 1.f/(1.f + __expf(-x));
}

// ---------- host ----------
extern "C" void kernel_launch(void* const* d_in, const int* in_sizes, int n_in,
                              void* d_out, int out_size, void* d_ws, size_t ws_size,
                              hipStream_t stream){
    const float* x_p  = (const float*)d_in[0];
    const float* x_c  = (const float*)d_in[1];
    const int*   src  = (const int*)d_in[2];
    const int*   dst  = (const int*)d_in[3];
    const int*   els  = (const int*)d_in[4];
    const int*   eld  = (const int*)d_in[5];
    const float* sage_pc_Wl = (const float*)d_in[6];
    const float* sage_pc_bl = (const float*)d_in[7];
    const float* sage_pc_Wr = (const float*)d_in[8];
    const float* sage_cp_Wl = (const float*)d_in[9];
    const float* sage_cp_bl = (const float*)d_in[10];
    const float* sage_cp_Wr = (const float*)d_in[11];
    const float* gat_pc_Wsrc = (const float*)d_in[12];
    const float* gat_pc_Wdst = (const float*)d_in[13];
    const float* gat_pc_asrc = (const float*)d_in[14];
    const float* gat_pc_adst = (const float*)d_in[15];
    const float* gat_pc_b    = (const float*)d_in[16];
    const float* gat_cp_Wsrc = (const float*)d_in[17];
    const float* gat_cp_Wdst = (const float*)d_in[18];
    const float* gat_cp_asrc = (const float*)d_in[19];
    const float* gat_cp_adst = (const float*)d_in[20];
    const float* gat_cp_b    = (const float*)d_in[21];
    const float* lin_p_W = (const float*)d_in[22];
    const float* lin_p_b = (const float*)d_in[23];
    const float* lin_c_W = (const float*)d_in[24];
    const float* lin_c_b = (const float*)d_in[25];
    const float* link_W  = (const float*)d_in[26];
    const float* link_b  = (const float*)d_in[27];

    const int E  = in_sizes[2];
    const int EL = in_sizes[4];

    float* ws = (float*)d_ws;
    size_t off = 0;
    auto alloc = [&](size_t n)->float*{ float* p = ws + off; off += (n + 3) & ~(size_t)3; return p; };

    unsigned short* BtP  = (unsigned short*)alloc((size_t)256*DIMP/2);
    float* WcatC = alloc((size_t)DIMC*256);
    unsigned short* BtSp = (unsigned short*)alloc((size_t)512*128/2);
    unsigned short* BtSc = (unsigned short*)alloc((size_t)512*128/2);
    unsigned short* P1   = (unsigned short*)alloc((size_t)NPROT*256/2);  // bf16 [NPROT][256]
    float* C1    = alloc((size_t)NCLS*256);                              // f32  [NCLS][256]
    unsigned short* h_p  = (unsigned short*)alloc((size_t)NPROT*128/2);
    unsigned short* h_c  = (unsigned short*)alloc((size_t)NCLS*128/2);
    unsigned short* hs_p = (unsigned short*)alloc((size_t)NPROT*512/2);  // bf16 [NPROT][512]
    unsigned short* hs_c = (unsigned short*)alloc((size_t)NCLS*512/2);
    float* attP  = alloc((size_t)NPROT*8);
    float* attC  = alloc((size_t)NCLS*8);
    float* projP = alloc(128*8);
    float* projC = alloc(128*8);
    float* w_p   = alloc(128);
    float* w_c   = alloc(128);
    float* cpc   = alloc(4);
    int* deg_c = (int*)alloc(NCLS);
    int* deg_p = (int*)alloc(NPROT);
    int* cur_c = (int*)alloc(NCLS);
    int* cur_p = (int*)alloc(NPROT);
    int* off_c = (int*)alloc(NCLS+1);
    int* off_p = (int*)alloc(NPROT+1);
    int* adj_c = (int*)alloc(E);
    int* adj_p = (int*)alloc(E);
    float* u_p = alloc(NPROT);
    float* u_c = alloc(NCLS);
    if(off*4 > ws_size) return;

    hipMemsetAsync(deg_c, 0, (size_t)NCLS*4, stream);
    hipMemsetAsync(deg_p, 0, (size_t)NPROT*4, stream);
    hipMemsetAsync(cur_c, 0, (size_t)NCLS*4, stream);
    hipMemsetAsync(cur_p, 0, (size_t)NPROT*4, stream);

    // --- weight prep ---
    build_btP<<<(256*DIMP+255)/256,256,0,stream>>>(sage_pc_Wl, sage_cp_Wr, BtP);
    build_cat<<<(DIMC*256+255)/256,256,0,stream>>>(sage_cp_Wl, sage_pc_Wr, WcatC, DIMC);
    build_btS<<<(512*128+255)/256,256,0,stream>>>(gat_pc_Wsrc, BtSp);
    build_btS<<<(512*128+255)/256,256,0,stream>>>(gat_cp_Wsrc, BtSc);
    fold_att<<<2,256,0,stream>>>(gat_pc_Wsrc, gat_pc_asrc, projP, 0);
    fold_att<<<2,256,0,stream>>>(gat_cp_Wdst, gat_cp_adst, projP, 4);
    fold_att<<<2,256,0,stream>>>(gat_pc_Wdst, gat_pc_adst, projC, 0);
    fold_att<<<2,256,0,stream>>>(gat_cp_Wsrc, gat_cp_asrc, projC, 4);
    fold_link<<<1,256,0,stream>>>(lin_p_W, lin_p_b, lin_c_W, lin_c_b, link_W, w_p, w_c, cpc);

    // --- CSR build ---
    deg_kernel<<<(E+255)/256,256,0,stream>>>(src,dst,deg_p,deg_c,E);
    scan_excl<<<1,1024,0,stream>>>(deg_c, off_c, NCLS);
    scan_excl<<<1,1024,0,stream>>>(deg_p, off_p, NPROT);
    csr_fill<<<(E+255)/256,256,0,stream>>>(src,dst,off_c,off_p,cur_c,cur_p,adj_c,adj_p,E);

    // --- layer 1 GEMMs ---
    gemm_p1<<<(NPROT+127)/128,512,0,stream>>>(x_p, BtP, P1, NPROT);
    gemm64<<<dim3(4,(NCLS+63)/64),256,0,stream>>>(x_c, WcatC, C1, NCLS, 256, DIMC);

    // --- SAGE (fused mean+bias+self+relu) ---
    sage_csr<1><<<(NCLS+3)/4,256,0,stream>>>(off_c, adj_c, (const void*)P1, (const void*)C1, sage_pc_bl, h_c, NCLS);
    sage_csr<0><<<(NPROT+3)/4,256,0,stream>>>(off_p, adj_p, (const void*)C1, (const void*)P1, sage_cp_bl, h_p, NPROT);

    // --- layer 2 GEMMs ---
    gemm_hs<<<dim3(4,(NPROT+127)/128),256,0,stream>>>(h_p, BtSp, hs_p, NPROT);
    gemm_hs<<<dim3(4,(NCLS +127)/128),256,0,stream>>>(h_c, BtSc, hs_c, NCLS);
    gemm_n8<<<(NPROT+31)/32,256,0,stream>>>(h_p, projP, attP, NPROT);
    gemm_n8<<<(NCLS +31)/32,256,0,stream>>>(h_c, projC, attC, NCLS);

    // --- fused GAT + output head ---
    gat_csr<<<NCLS,128,0,stream>>>(off_c, adj_c, attP, 0, attC, 0, hs_p, gat_pc_b, w_c, cpc, 1, u_c, NCLS);
    gat_csr<<<NPROT,128,0,stream>>>(off_p, adj_p, attC, 4, attP, 4, hs_c, gat_cp_b, w_p, cpc, 0, u_p, NPROT);

    link_out<<<(EL+255)/256,256,0,stream>>>(els, eld, u_p, u_c, link_b, (float*)d_out, EL);
}

// Round 4
// 360.282 us; speedup vs baseline: 3.4243x; 1.4719x over previous
//
#include <hip/hip_runtime.h>
#include <math.h>

#define NPROT 50000
#define NCLS  5000
#define DIMP  1280
#define DIMC  256
#define SCAN_N (NCLS + NPROT)

typedef float4 f4;
typedef __attribute__((ext_vector_type(8))) short short8;
typedef __attribute__((ext_vector_type(4))) float f32x4;

// ---------- helpers ----------
__device__ __forceinline__ unsigned short f2bf(float f){   // RNE
    unsigned u = __float_as_uint(f);
    u += 0x7FFFu + ((u >> 16) & 1u);
    return (unsigned short)(u >> 16);
}
__device__ __forceinline__ float bf2f(unsigned short b){
    return __uint_as_float(((unsigned)b) << 16);
}
__device__ __forceinline__ void gload_lds16(const void* g, void* l){
    __builtin_amdgcn_global_load_lds((const __attribute__((address_space(1))) void*)g,
                                     (__attribute__((address_space(3))) void*)l, 16, 0, 0);
}

// ---------- P1 GEMM: C_bf16[M,256] = A_f32[M,1280] @ Bt_bf16[256,1280]^T ----------
__global__ __launch_bounds__(512) void gemm_p1(const float* __restrict__ Af,
                                               const unsigned short* __restrict__ Bt,
                                               unsigned short* __restrict__ C, int M){
    __shared__ __align__(16) unsigned char As[128*32*4];
    __shared__ __align__(16) unsigned char Bs[256*32*2];
    const int tid  = threadIdx.x;
    const int lane = tid & 63;
    const int w    = tid >> 6;
    const int wm   = w >> 2, wn = w & 3;
    const int row0 = blockIdx.x * 128;
    const int kg = lane >> 4, fr = lane & 15;

    f32x4 acc[4][4] = {};

    for(int k0 = 0; k0 < DIMP; k0 += 32){
        #pragma unroll
        for(int i=0;i<2;i++){
            int c  = i*512 + w*64 + lane;
            int r  = c >> 3, cc = c & 7;
            int scc = cc ^ (r & 7);
            int srow = min(row0 + r, M-1);
            gload_lds16((const void*)(Af + (size_t)srow*DIMP + k0 + scc*4),
                        (void*)(As + (i*512 + w*64)*16));
        }
        #pragma unroll
        for(int i=0;i<2;i++){
            int c  = i*512 + w*64 + lane;
            int r  = c >> 2, cc = c & 3;
            int scc = cc ^ ((r>>1) & 3);
            gload_lds16((const void*)(Bt + (size_t)r*DIMP + k0 + scc*8),
                        (void*)(Bs + (i*512 + w*64)*16));
        }
        __syncthreads();

        short8 aF[4], bF[4];
        #pragma unroll
        for(int m=0;m<4;m++){
            int r = wm*64 + m*16 + fr;
            int b0 = r*128 + kg*32;
            f4 lo = *(const f4*)(As + (( b0      ) ^ ((r&7)<<4)));
            f4 hi = *(const f4*)(As + (( b0 + 16 ) ^ ((r&7)<<4)));
            union { short8 s; unsigned short u[8]; } uu;
            uu.u[0]=f2bf(lo.x); uu.u[1]=f2bf(lo.y); uu.u[2]=f2bf(lo.z); uu.u[3]=f2bf(lo.w);
            uu.u[4]=f2bf(hi.x); uu.u[5]=f2bf(hi.y); uu.u[6]=f2bf(hi.z); uu.u[7]=f2bf(hi.w);
            aF[m] = uu.s;
        }
        #pragma unroll
        for(int n=0;n<4;n++){
            int r = wn*64 + n*16 + fr;
            int b0 = (r*64 + kg*16) ^ (((r>>1)&3)<<4);
            bF[n] = *(const short8*)(Bs + b0);
        }
        #pragma unroll
        for(int m=0;m<4;m++)
        #pragma unroll
        for(int n=0;n<4;n++)
            acc[m][n] = __builtin_amdgcn_mfma_f32_16x16x32_bf16(aF[m], bF[n], acc[m][n], 0, 0, 0);
        __syncthreads();
    }

    #pragma unroll
    for(int m=0;m<4;m++)
    #pragma unroll
    for(int r=0;r<4;r++){
        int row = row0 + wm*64 + m*16 + kg*4 + r;
        if(row < M){
            #pragma unroll
            for(int n=0;n<4;n++)
                C[(size_t)row*256 + wn*64 + n*16 + fr] = f2bf(acc[m][n][r]);
        }
    }
}

// ---------- hs GEMM (both node types): C_bf16[*,512] = A_bf16[*,128] @ Bt^T ----------
#define NPB ((NPROT+127)/128)
#define NCB ((NCLS+127)/128)
__global__ __launch_bounds__(256) void gemm_hs(const unsigned short* __restrict__ Ap,
                                               const unsigned short* __restrict__ Ac,
                                               const unsigned short* __restrict__ Btp,
                                               const unsigned short* __restrict__ Btc,
                                               unsigned short* __restrict__ Cp,
                                               unsigned short* __restrict__ Cc){
    const bool cls = (int)blockIdx.y >= NPB;
    const unsigned short* A  = cls ? Ac : Ap;
    const unsigned short* Bt = cls ? Btc : Btp;
    unsigned short* C = cls ? Cc : Cp;
    const int M = cls ? NCLS : NPROT;
    const int row0 = (cls ? blockIdx.y - NPB : blockIdx.y) * 128;
    const int col0 = blockIdx.x * 128;

    __shared__ __align__(16) unsigned char As[128*32*2];
    __shared__ __align__(16) unsigned char Bs[128*32*2];
    const int tid  = threadIdx.x;
    const int lane = tid & 63;
    const int w    = tid >> 6;
    const int wm   = w >> 1, wn = w & 1;
    const int kg = lane >> 4, fr = lane & 15;

    f32x4 acc[4][4] = {};

    for(int k0 = 0; k0 < 128; k0 += 32){
        #pragma unroll
        for(int i=0;i<2;i++){
            int c  = i*256 + w*64 + lane;
            int r  = c >> 2, cc = c & 3;
            int scc = cc ^ ((r>>1) & 3);
            int srow = min(row0 + r, M-1);
            gload_lds16((const void*)(A + (size_t)srow*128 + k0 + scc*8),
                        (void*)(As + (i*256 + w*64)*16));
        }
        #pragma unroll
        for(int i=0;i<2;i++){
            int c  = i*256 + w*64 + lane;
            int r  = c >> 2, cc = c & 3;
            int scc = cc ^ ((r>>1) & 3);
            gload_lds16((const void*)(Bt + (size_t)(col0 + r)*128 + k0 + scc*8),
                        (void*)(Bs + (i*256 + w*64)*16));
        }
        __syncthreads();

        short8 aF[4], bF[4];
        #pragma unroll
        for(int m=0;m<4;m++){
            int r = wm*64 + m*16 + fr;
            int b0 = (r*64 + kg*16) ^ (((r>>1)&3)<<4);
            aF[m] = *(const short8*)(As + b0);
        }
        #pragma unroll
        for(int n=0;n<4;n++){
            int r = wn*64 + n*16 + fr;
            int b0 = (r*64 + kg*16) ^ (((r>>1)&3)<<4);
            bF[n] = *(const short8*)(Bs + b0);
        }
        #pragma unroll
        for(int m=0;m<4;m++)
        #pragma unroll
        for(int n=0;n<4;n++)
            acc[m][n] = __builtin_amdgcn_mfma_f32_16x16x32_bf16(aF[m], bF[n], acc[m][n], 0, 0, 0);
        __syncthreads();
    }

    #pragma unroll
    for(int m=0;m<4;m++)
    #pragma unroll
    for(int r=0;r<4;r++){
        int row = row0 + wm*64 + m*16 + kg*4 + r;
        if(row < M){
            #pragma unroll
            for(int n=0;n<4;n++)
                C[(size_t)row*512 + col0 + wn*64 + n*16 + fr] = f2bf(acc[m][n][r]);
        }
    }
}

// ---------- f32 tiled GEMM (class-side C1) ----------
__global__ __launch_bounds__(256) void gemm64(const float* __restrict__ A,
                                              const float* __restrict__ B,
                                              float* __restrict__ C,
                                              int M, int N, int K){
    __shared__ __align__(16) float As[16][68];
    __shared__ __align__(16) float Bs[16][64];
    const int tid = threadIdx.x;
    const int row0 = blockIdx.y * 64;
    const int col0 = blockIdx.x * 64;
    const int ty = tid >> 4;
    const int tx = tid & 15;
    const int m  = tid >> 2;
    const int kq = (tid & 3) << 2;
    const int kb = tid >> 4;
    const int c4 = (tid & 15) << 2;

    float acc[4][4];
#pragma unroll
    for(int i=0;i<4;i++)
#pragma unroll
        for(int j=0;j<4;j++) acc[i][j]=0.f;

    const bool arow_ok = (row0 + m) < M;
    const float* Abase = A + (size_t)(row0 + m) * K + kq;
    const float* Bbase = B + col0 + c4 + (size_t)kb * N;

    for(int k0 = 0; k0 < K; k0 += 16){
        f4 av;
        if(arow_ok) av = *(const f4*)(Abase + k0);
        else        av = make_float4(0.f,0.f,0.f,0.f);
        As[kq+0][m]=av.x; As[kq+1][m]=av.y; As[kq+2][m]=av.z; As[kq+3][m]=av.w;
        *(f4*)&Bs[kb][c4] = *(const f4*)(Bbase + (size_t)k0 * N);
        __syncthreads();
#pragma unroll
        for(int kk=0;kk<16;kk++){
            f4 a = *(const f4*)&As[kk][ty<<2];
            f4 b = *(const f4*)&Bs[kk][tx<<2];
            float ar[4]={a.x,a.y,a.z,a.w};
            float br[4]={b.x,b.y,b.z,b.w};
#pragma unroll
            for(int i=0;i<4;i++)
#pragma unroll
                for(int j=0;j<4;j++) acc[i][j] += ar[i]*br[j];
        }
        __syncthreads();
    }
#pragma unroll
    for(int i=0;i<4;i++){
        int r = row0 + (ty<<2) + i;
        if(r < M){
            f4 v = make_float4(acc[i][0],acc[i][1],acc[i][2],acc[i][3]);
            *(f4*)&C[(size_t)r*N + col0 + (tx<<2)] = v;
        }
    }
}

// ---------- narrow GEMM both types: att[row,0:8] ----------
__global__ __launch_bounds__(256) void gemm_n8_all(const unsigned short* __restrict__ h_p,
                                                   const unsigned short* __restrict__ h_c,
                                                   const float* __restrict__ projP,
                                                   const float* __restrict__ projC,
                                                   float* __restrict__ attP,
                                                   float* __restrict__ attC){
    __shared__ float Bs[2048];
    const int tid = threadIdx.x;
    for(int i=tid;i<1024;i+=256){ Bs[i]=projP[i]; Bs[1024+i]=projC[i]; }
    __syncthreads();
    const int row = blockIdx.x*32 + (tid>>3);
    const int j = tid & 7;
    if(row >= NPROT+NCLS) return;
    const bool cls = row >= NPROT;
    const int r = cls ? row - NPROT : row;
    const unsigned short* a = (cls ? h_c : h_p) + (size_t)r*128;
    const float* B = Bs + (cls ? 1024 : 0);
    float s=0.f;
#pragma unroll
    for(int k=0;k<128;k++) s += bf2f(a[k])*B[k*8+j];
    (cls ? attC : attP)[(size_t)r*8+j]=s;
}

// ---------- merged weight prep ----------
// seg0: BtP[256][1280]  seg1: WcatC[256][256]  seg2: BtSp[512][128]  seg3: BtSc
__global__ void prep_weights(const float* __restrict__ Wl_pc, const float* __restrict__ Wr_cp,
                             const float* __restrict__ Wl_cp, const float* __restrict__ Wr_pc,
                             const float* __restrict__ Ws_pc, const float* __restrict__ Ws_cp,
                             unsigned short* __restrict__ BtP, float* __restrict__ WcatC,
                             unsigned short* __restrict__ BtSp, unsigned short* __restrict__ BtSc){
    int t = blockIdx.x*256 + threadIdx.x;
    if(t < 327680){
        int n = t / 1280, k = t % 1280;
        float v = (n<128) ? Wl_pc[(size_t)k*128+n] : Wr_cp[(size_t)k*128+n-128];
        BtP[t] = f2bf(v);
    } else if(t < 393216){
        int i = t - 327680; int k = i>>8, j = i&255;
        WcatC[i] = (j<128) ? Wl_cp[(size_t)k*128+j] : Wr_pc[(size_t)k*128+j-128];
    } else if(t < 458752){
        int i = t - 393216; int n = i>>7, k = i&127;
        BtSp[i] = f2bf(Ws_pc[(size_t)k*512+n]);
    } else {
        int i = t - 458752; int n = i>>7, k = i&127;
        BtSc[i] = f2bf(Ws_cp[(size_t)k*512+n]);
    }
}

// ---------- merged folds: blocks 0..7 = fold_att sections, block 8 = fold_link ----------
__global__ void folds(const float* __restrict__ pcWs, const float* __restrict__ pcAs,
                      const float* __restrict__ pcWd, const float* __restrict__ pcAd,
                      const float* __restrict__ cpWs, const float* __restrict__ cpAs,
                      const float* __restrict__ cpWd, const float* __restrict__ cpAd,
                      const float* __restrict__ lpW, const float* __restrict__ lpb,
                      const float* __restrict__ lcW, const float* __restrict__ lcb,
                      const float* __restrict__ linkW,
                      float* __restrict__ projP, float* __restrict__ projC,
                      float* __restrict__ w_p, float* __restrict__ w_c,
                      float* __restrict__ cpc){
    int blk = blockIdx.x, tid = threadIdx.x;
    if(blk < 8){
        int sec = blk >> 1;
        int t = (blk & 1)*256 + tid;    // 0..511
        const float *W, *a; float* proj; int colbase;
        if(sec==0){ W=pcWs; a=pcAs; proj=projP; colbase=0; }
        else if(sec==1){ W=cpWd; a=cpAd; proj=projP; colbase=4; }
        else if(sec==2){ W=pcWd; a=pcAd; proj=projC; colbase=0; }
        else { W=cpWs; a=cpAs; proj=projC; colbase=4; }
        int k = t >> 2, h = t & 3;
        const float* w = W + (size_t)k*512 + h*128;
        const float* av = a + h*128;
        float s=0.f;
        for(int c=0;c<128;c++) s += w[c]*av[c];
        proj[k*8 + colbase + h] = s;
    } else {
        if(tid < 128){
            float s=0.f;
            for(int o=0;o<128;o++) s += lpW[(size_t)tid*128+o]*linkW[o];
            w_p[tid]=s;
        } else {
            int j=tid-128;
            float s=0.f;
            for(int o=0;o<128;o++) s += lcW[(size_t)j*128+o]*linkW[128+o];
            w_c[j]=s;
        }
        if(tid==0){ float s=0.f; for(int o=0;o<128;o++) s+=lpb[o]*linkW[o];      cpc[0]=s; }
        if(tid==1){ float s=0.f; for(int o=0;o<128;o++) s+=lcb[o]*linkW[128+o];  cpc[1]=s; }
    }
}

// ---------- CSR: degrees over concatenated [class | prot] ----------
__global__ void deg_kernel(const int* __restrict__ src, const int* __restrict__ dst,
                           int* __restrict__ deg, int E){
    int e = blockIdx.x*256 + threadIdx.x;
    if(e>=E) return;
    atomicAdd(&deg[dst[e]],1);
    atomicAdd(&deg[NCLS + src[e]],1);
}

// ---------- hierarchical exclusive scan ----------
__global__ __launch_bounds__(1024) void scan1(const int* __restrict__ in, int* __restrict__ out,
                                              int* __restrict__ part, int n){
    __shared__ int buf[1024];
    int tid = threadIdx.x;
    int g = blockIdx.x*1024 + tid;
    int v = (g<n) ? in[g] : 0;
    buf[tid] = v;
    __syncthreads();
    for(int o=1;o<1024;o<<=1){
        int t = (tid>=o) ? buf[tid-o] : 0;
        __syncthreads();
        buf[tid] += t;
        __syncthreads();
    }
    if(g<n) out[g] = buf[tid] - v;
    if(tid==1023) part[blockIdx.x] = buf[1023];
}
__global__ __launch_bounds__(64) void scan2(int* __restrict__ part, int nb,
                                            int* __restrict__ out, int n){
    int tid = threadIdx.x;
    int orig = (tid<nb) ? part[tid] : 0;
    int v = orig;
    #pragma unroll
    for(int o=1;o<64;o<<=1){
        int t = __shfl_up(v, o);
        if(tid>=o) v += t;
    }
    if(tid<nb) part[tid] = v - orig;    // exclusive
    if(tid==63) out[n] = v;             // grand total (nb<=64)
}
__global__ __launch_bounds__(1024) void scan3(int* __restrict__ out, const int* __restrict__ part, int n){
    int g = blockIdx.x*1024 + threadIdx.x;
    if(g<n) out[g] += part[blockIdx.x];
}

__global__ void csr_fill(const int* __restrict__ src, const int* __restrict__ dst,
                         const int* __restrict__ off, int* __restrict__ cur,
                         int* __restrict__ adj, int E){
    int e = blockIdx.x*256 + threadIdx.x;
    if(e>=E) return;
    int s = src[e], d = dst[e];
    int pc = atomicAdd(&cur[d],1);        adj[off[d]+pc] = s;
    int pp = atomicAdd(&cur[NCLS+s],1);   adj[off[NCLS+s]+pp] = d;
}

// ---------- merged SAGE (both types) ----------
__global__ __launch_bounds__(256) void sage_all(const int* __restrict__ off, const int* __restrict__ adj,
                                                const unsigned short* __restrict__ P1, const float* __restrict__ C1,
                                                const float* __restrict__ bl_pc, const float* __restrict__ bl_cp,
                                                unsigned short* __restrict__ h_c, unsigned short* __restrict__ h_p){
    int v = blockIdx.x*4 + (threadIdx.x>>6);
    int l = threadIdx.x & 63;
    if(v >= SCAN_N) return;
    int b = off[v], deg = off[v+1]-b;
    float a0=0.f, a1=0.f;
    float inv = 1.f/(float)max(deg,1);
    if(v < NCLS){
        for(int i=0;i<deg;i++){
            int s = adj[b+i];
            ushort2 w = *((const ushort2*)P1 + (size_t)s*128 + l);
            a0 += bf2f(w.x); a1 += bf2f(w.y);
        }
        float2 sv = *((const float2*)C1 + (size_t)v*128 + 64 + l);
        float h0 = fmaxf(a0*inv + bl_pc[2*l]   + sv.x, 0.f);
        float h1 = fmaxf(a1*inv + bl_pc[2*l+1] + sv.y, 0.f);
        ushort2 o; o.x=f2bf(h0); o.y=f2bf(h1);
        *((ushort2*)h_c + (size_t)v*64 + l) = o;
    } else {
        int m = v - NCLS;
        for(int i=0;i<deg;i++){
            int d = adj[b+i];
            float2 w = *((const float2*)C1 + (size_t)d*128 + l);
            a0 += w.x; a1 += w.y;
        }
        ushort2 sv = *((const ushort2*)P1 + (size_t)m*128 + 64 + l);
        float h0 = fmaxf(a0*inv + bl_cp[2*l]   + bf2f(sv.x), 0.f);
        float h1 = fmaxf(a1*inv + bl_cp[2*l+1] + bf2f(sv.y), 0.f);
        ushort2 o; o.x=f2bf(h0); o.y=f2bf(h1);
        *((ushort2*)h_p + (size_t)m*64 + l) = o;
    }
}

// ---------- merged fused GAT + head-mean + relu + output dot (both types) ----------
__global__ __launch_bounds__(128) void gat_all(const int* __restrict__ off, const int* __restrict__ adj,
                                               const float* __restrict__ attP, const float* __restrict__ attC,
                                               const unsigned short* __restrict__ hs_p,
                                               const unsigned short* __restrict__ hs_c,
                                               const float* __restrict__ gb_pc, const float* __restrict__ gb_cp,
                                               const float* __restrict__ w_c, const float* __restrict__ w_p,
                                               const float* __restrict__ cpc,
                                               float* __restrict__ u_c, float* __restrict__ u_p){
    __shared__ float ald[4];
    __shared__ int   adjS[32];
    __shared__ float eeS[32*4];
    __shared__ float red[128];
    __shared__ float den4[4];
    __shared__ float ws2[2];

    int n = blockIdx.x;
    const bool cls = n < NCLS;
    const int node = cls ? n : n - NCLS;
    const float* attS = cls ? attP : attC;
    const float* attD = cls ? attC : attP;
    const int sbase = cls ? 0 : 4;
    const int dbase = cls ? 0 : 4;
    const unsigned short* hs = cls ? hs_p : hs_c;
    const float* gb = cls ? gb_pc : gb_cp;
    const float* wv = cls ? w_c : w_p;
    float* u = cls ? u_c : u_p;
    const int cidx = cls ? 1 : 0;

    int j = threadIdx.x;
    int b = off[n], deg = off[n+1]-b;
    if(j < 4) ald[j] = attD[(size_t)node*8 + dbase + j];

    float acc0=0.f, acc1=0.f, acc2=0.f, acc3=0.f;
    float denP = 0.f;

    for(int base=0; base<deg; base+=32){
        int cnt = min(32, deg-base);
        if(j < cnt) adjS[j] = adj[b+base+j];
        __syncthreads();
        if(j < cnt*4){
            int i = j>>2, h = j&3;
            int s = adjS[i];
            float e = attS[(size_t)s*8 + sbase + h] + ald[h];
            e = e > 0.f ? e : 0.2f*e;
            float ee = __expf(e);
            eeS[j] = ee;
            denP += ee;
        }
        __syncthreads();
        for(int ii=0; ii<cnt; ii++){
            int s = adjS[ii];
            const unsigned short* row = hs + (size_t)s*512;
            float4 ee = *(const float4*)&eeS[ii*4];
            acc0 += ee.x * bf2f(row[j]);
            acc1 += ee.y * bf2f(row[128+j]);
            acc2 += ee.z * bf2f(row[256+j]);
            acc3 += ee.w * bf2f(row[384+j]);
        }
        __syncthreads();
    }

    red[j] = denP;
    __syncthreads();
    if(j < 4){
        float s = 0.f;
        for(int t=j; t<128; t+=4) s += red[t];
        den4[j] = s;
    }
    __syncthreads();

    float outj = 0.f;
    if(deg > 0)
        outj = 0.25f*(acc0/den4[0] + acc1/den4[1] + acc2/den4[2] + acc3/den4[3]);

    float val = fmaxf(outj + gb[j], 0.f) * wv[j];
    #pragma unroll
    for(int o=32;o;o>>=1) val += __shfl_down(val, o);
    if((j & 63) == 0) ws2[j>>6] = val;
    __syncthreads();
    if(j == 0) u[node] = ws2[0] + ws2[1] + cpc[cidx];
}

__global__ void link_out(const int* __restrict__ els, const int* __restrict__ eld,
                         const float* __restrict__ u_p, const float* __restrict__ u_c,
                         const float* __restrict__ linkb, float* __restrict__ out, int EL){
    int i = blockIdx.x*256 + threadIdx.x;
    if(i >= EL) return;
    float x = u_p[els[i]] + u_c[eld[i]] + linkb[0];
    out[i] = 1.f/(1.f + __expf(-x));
}

// ---------- host ----------
extern "C" void kernel_launch(void* const* d_in, const int* in_sizes, int n_in,
                              void* d_out, int out_size, void* d_ws, size_t ws_size,
                              hipStream_t stream){
    const float* x_p  = (const float*)d_in[0];
    const float* x_c  = (const float*)d_in[1];
    const int*   src  = (const int*)d_in[2];
    const int*   dst  = (const int*)d_in[3];
    const int*   els  = (const int*)d_in[4];
    const int*   eld  = (const int*)d_in[5];
    const float* sage_pc_Wl = (const float*)d_in[6];
    const float* sage_pc_bl = (const float*)d_in[7];
    const float* sage_pc_Wr = (const float*)d_in[8];
    const float* sage_cp_Wl = (const float*)d_in[9];
    const float* sage_cp_bl = (const float*)d_in[10];
    const float* sage_cp_Wr = (const float*)d_in[11];
    const float* gat_pc_Wsrc = (const float*)d_in[12];
    const float* gat_pc_Wdst = (const float*)d_in[13];
    const float* gat_pc_asrc = (const float*)d_in[14];
    const float* gat_pc_adst = (const float*)d_in[15];
    const float* gat_pc_b    = (const float*)d_in[16];
    const float* gat_cp_Wsrc = (const float*)d_in[17];
    const float* gat_cp_Wdst = (const float*)d_in[18];
    const float* gat_cp_asrc = (const float*)d_in[19];
    const float* gat_cp_adst = (const float*)d_in[20];
    const float* gat_cp_b    = (const float*)d_in[21];
    const float* lin_p_W = (const float*)d_in[22];
    const float* lin_p_b = (const float*)d_in[23];
    const float* lin_c_W = (const float*)d_in[24];
    const float* lin_c_b = (const float*)d_in[25];
    const float* link_W  = (const float*)d_in[26];
    const float* link_b  = (const float*)d_in[27];

    const int E  = in_sizes[2];
    const int EL = in_sizes[4];

    float* ws = (float*)d_ws;
    size_t off = 0;
    auto alloc = [&](size_t n)->float*{ float* p = ws + off; off += (n + 3) & ~(size_t)3; return p; };

    unsigned short* BtP  = (unsigned short*)alloc((size_t)256*DIMP/2);
    float* WcatC = alloc((size_t)DIMC*256);
    unsigned short* BtSp = (unsigned short*)alloc((size_t)512*128/2);
    unsigned short* BtSc = (unsigned short*)alloc((size_t)512*128/2);
    unsigned short* P1   = (unsigned short*)alloc((size_t)NPROT*256/2);
    float* C1    = alloc((size_t)NCLS*256);
    unsigned short* h_p  = (unsigned short*)alloc((size_t)NPROT*128/2);
    unsigned short* h_c  = (unsigned short*)alloc((size_t)NCLS*128/2);
    unsigned short* hs_p = (unsigned short*)alloc((size_t)NPROT*512/2);
    unsigned short* hs_c = (unsigned short*)alloc((size_t)NCLS*512/2);
    float* attP  = alloc((size_t)NPROT*8);
    float* attC  = alloc((size_t)NCLS*8);
    float* projP = alloc(128*8);
    float* projC = alloc(128*8);
    float* w_p   = alloc(128);
    float* w_c   = alloc(128);
    float* cpc   = alloc(4);
    int* degcur = (int*)alloc((size_t)2*SCAN_N);   // deg | cur (one memset)
    int* deg = degcur;
    int* cur = degcur + SCAN_N;
    int* offv = (int*)alloc(SCAN_N+1);
    int* part = (int*)alloc(64);
    int* adj  = (int*)alloc((size_t)2*E);
    float* u_p = alloc(NPROT);
    float* u_c = alloc(NCLS);
    if(off*4 > ws_size) return;

    hipMemsetAsync(degcur, 0, (size_t)2*SCAN_N*4, stream);

    // --- weight prep (merged) ---
    prep_weights<<<2048,256,0,stream>>>(sage_pc_Wl, sage_cp_Wr, sage_cp_Wl, sage_pc_Wr,
                                        gat_pc_Wsrc, gat_cp_Wsrc, BtP, WcatC, BtSp, BtSc);
    folds<<<9,256,0,stream>>>(gat_pc_Wsrc, gat_pc_asrc, gat_pc_Wdst, gat_pc_adst,
                              gat_cp_Wsrc, gat_cp_asrc, gat_cp_Wdst, gat_cp_adst,
                              lin_p_W, lin_p_b, lin_c_W, lin_c_b, link_W,
                              projP, projC, w_p, w_c, cpc);

    // --- CSR build (hierarchical scan over [deg_c | deg_p]) ---
    deg_kernel<<<(E+255)/256,256,0,stream>>>(src,dst,deg,E);
    const int NB = (SCAN_N + 1023)/1024;
    scan1<<<NB,1024,0,stream>>>(deg, offv, part, SCAN_N);
    scan2<<<1,64,0,stream>>>(part, NB, offv, SCAN_N);
    scan3<<<NB,1024,0,stream>>>(offv, part, SCAN_N);
    csr_fill<<<(E+255)/256,256,0,stream>>>(src,dst,offv,cur,adj,E);

    // --- layer 1 GEMMs ---
    gemm_p1<<<(NPROT+127)/128,512,0,stream>>>(x_p, BtP, P1, NPROT);
    gemm64<<<dim3(4,(NCLS+63)/64),256,0,stream>>>(x_c, WcatC, C1, NCLS, 256, DIMC);

    // --- SAGE (merged both types) ---
    sage_all<<<(SCAN_N+3)/4,256,0,stream>>>(offv, adj, P1, C1, sage_pc_bl, sage_cp_bl, h_c, h_p);

    // --- layer 2 GEMMs ---
    gemm_hs<<<dim3(4,NPB+NCB),256,0,stream>>>(h_p, h_c, BtSp, BtSc, hs_p, hs_c);
    gemm_n8_all<<<(NPROT+NCLS+31)/32,256,0,stream>>>(h_p, h_c, projP, projC, attP, attC);

    // --- fused GAT + output head (merged both types) ---
    gat_all<<<SCAN_N,128,0,stream>>>(offv, adj, attP, attC, hs_p, hs_c,
                                     gat_pc_b, gat_cp_b, w_c, w_p, cpc, u_c, u_p);

    link_out<<<(EL+255)/256,256,0,stream>>>(els, eld, u_p, u_c, link_b, (float*)d_out, EL);
}